// Round 1
// baseline (973.046 us; speedup 1.0000x reference)
//
#include <hip/hip_runtime.h>
#include <math.h>

#define NN 40000
#define CC 128
#define KK 64
#define BATCH 2
#define NLAYER 4
#define SPLITS 128
#define NT 64
#define NCHUNK 625   // NN / NT
#define AR 260       // padded row stride of assembled A matrix

__device__ __forceinline__ float gelu_exact(float x) {
    return 0.5f * x * (1.0f + erff(x * 0.70710678118654752f));
}

// ---------------- basis: bc = cos(nodes.modes)*mask, bs = sin(...)*mask ----------------
__global__ void basis_kernel(const float* __restrict__ nodes, const float* __restrict__ mask,
                             const float* __restrict__ modes,
                             float* __restrict__ bc, float* __restrict__ bs) {
    __shared__ float sm[KK * 2];
    int t = threadIdx.x;
    if (t < KK * 2) sm[t] = modes[t];
    __syncthreads();
    int idx = blockIdx.x * 256 + t;
    if (idx >= BATCH * NN) return;
    int b = idx / NN, n = idx - b * NN;
    float nx = nodes[(long)idx * 2 + 0], ny = nodes[(long)idx * 2 + 1];
    float m = mask[idx];
    long base = (long)b * KK * NN + n;
    #pragma unroll 8
    for (int k = 0; k < KK; ++k) {
        float tv = nx * sm[2 * k] + ny * sm[2 * k + 1];
        float s, c;
        __sincosf(tv, &s, &c);
        bc[base + (long)k * NN] = c * m;
        bs[base + (long)k * NN] = s * m;
    }
}

// ---------------- lift: h[b,c,n] = x[b,n,:] @ fc0_w[:,c] + fc0_b[c] ----------------
__global__ void lift_kernel(const float* __restrict__ x, const float* __restrict__ w,
                            const float* __restrict__ bvec, float* __restrict__ h) {
    long idx = (long)blockIdx.x * 256 + threadIdx.x;
    if (idx >= (long)BATCH * CC * NN) return;
    int n = (int)(idx % NN);
    int bc_ = (int)(idx / NN);
    int c = bc_ % CC, b = bc_ / CC;
    const float* xr = x + ((long)b * NN + n) * 3;
    float acc = bvec[c] + xr[0] * w[c] + xr[1] * w[CC + c] + xr[2] * w[2 * CC + c];
    h[idx] = acc;
}

// ---------------- forward transform: xc/xs/x0 partial sums over an n-range ----------------
// block tile: [64 c] x [64 k], 128 threads, 8c x 4k per thread. grid (SPLITS, CC/64, BATCH)
__global__ __launch_bounds__(128) void forward_kernel(
        const float* __restrict__ h, const float* __restrict__ bc, const float* __restrict__ bs,
        const float* __restrict__ wts, const float* __restrict__ mask,
        float* __restrict__ pxc, float* __restrict__ pxs, float* __restrict__ px0) {
    int split = blockIdx.x, ct = blockIdx.y, b = blockIdx.z;
    int t = threadIdx.x;
    int tk = t & 15, tc = t >> 4;            // tk 0..15, tc 0..7
    __shared__ float sh[64][NT + 4];
    __shared__ float scb[64][NT + 4];
    __shared__ float ssb[64][NT + 4];
    __shared__ float swm[NT];
    float accC[8][4], accS[8][4], acc0[8];
    #pragma unroll
    for (int j = 0; j < 8; ++j) {
        acc0[j] = 0.f;
        #pragma unroll
        for (int q = 0; q < 4; ++q) { accC[j][q] = 0.f; accS[j][q] = 0.f; }
    }
    const float* hb  = h  + ((long)b * CC + ct * 64) * NN;
    const float* bcb = bc + (long)b * KK * NN;
    const float* bsb = bs + (long)b * KK * NN;
    const float* wb  = wts + (long)b * NN;
    const float* mb  = mask + (long)b * NN;

    for (int chunk = split; chunk < NCHUNK; chunk += SPLITS) {
        int n0 = chunk * NT;
        __syncthreads();
        int rr = t >> 4;
        int col = (t & 15) * 4;
        float4 wv = *(const float4*)(wb + n0 + col);
        #pragma unroll
        for (int i = 0; i < 8; ++i) {
            int r = i * 8 + rr;
            float4 hv = *(const float4*)(hb + (long)r * NN + n0 + col);
            *(float4*)&sh[r][col] = hv;
            float4 cv = *(const float4*)(bcb + (long)r * NN + n0 + col);
            cv.x *= wv.x; cv.y *= wv.y; cv.z *= wv.z; cv.w *= wv.w;
            *(float4*)&scb[r][col] = cv;
            float4 sv = *(const float4*)(bsb + (long)r * NN + n0 + col);
            sv.x *= wv.x; sv.y *= wv.y; sv.z *= wv.z; sv.w *= wv.w;
            *(float4*)&ssb[r][col] = sv;
        }
        if (t < NT) swm[t] = wb[n0 + t] * mb[n0 + t];
        __syncthreads();
        for (int nn = 0; nn < NT; ++nn) {
            float hv[8], cv[4], sv[4];
            #pragma unroll
            for (int j = 0; j < 8; ++j) hv[j] = sh[tc + 8 * j][nn];
            #pragma unroll
            for (int q = 0; q < 4; ++q) { cv[q] = scb[tk + 16 * q][nn]; sv[q] = ssb[tk + 16 * q][nn]; }
            #pragma unroll
            for (int j = 0; j < 8; ++j)
                #pragma unroll
                for (int q = 0; q < 4; ++q) {
                    accC[j][q] += hv[j] * cv[q];
                    accS[j][q] += hv[j] * sv[q];
                }
            if (tk == 0) {
                float wm = swm[nn];
                #pragma unroll
                for (int j = 0; j < 8; ++j) acc0[j] += hv[j] * wm;
            }
        }
    }
    long pb = ((long)split * BATCH + b) * (CC * KK);
    #pragma unroll
    for (int j = 0; j < 8; ++j) {
        int cg = ct * 64 + tc + 8 * j;
        #pragma unroll
        for (int q = 0; q < 4; ++q) {
            int k = tk + 16 * q;
            pxc[pb + (long)cg * KK + k] = accC[j][q];
            pxs[pb + (long)cg * KK + k] = accS[j][q];
        }
    }
    if (tk == 0) {
        long p0 = ((long)split * BATCH + b) * CC;
        #pragma unroll
        for (int j = 0; j < 8; ++j) px0[p0 + ct * 64 + tc + 8 * j] = acc0[j];
    }
}

// ---------------- reduce split-K partials ----------------
__global__ void reduce_kernel(const float* __restrict__ pxc, const float* __restrict__ pxs,
                              const float* __restrict__ px0,
                              float* __restrict__ xc, float* __restrict__ xs, float* __restrict__ x0) {
    int idx = blockIdx.x * 256 + threadIdx.x;
    if (idx < BATCH * CC * KK) {
        float a = 0.f, c = 0.f;
        for (int s = 0; s < SPLITS; ++s) {
            a += pxc[(long)s * (BATCH * CC * KK) + idx];
            c += pxs[(long)s * (BATCH * CC * KK) + idx];
        }
        xc[idx] = a;
        xs[idx] = c;
        if (idx < BATCH * CC) {
            float z = 0.f;
            for (int s = 0; s < SPLITS; ++s) z += px0[(long)s * (BATCH * CC) + idx];
            x0[idx] = z;
        }
    }
}

// ---------------- mix: assemble A = [2*fc | -2*fs | w_w | f0 | w_b] ----------------
// xc stored = +sum(h*wbc); xs stored = +sum(h*wbs); ref xs = -stored.
// fc = xc@wc - (ref xs)@ws = xc@wc + xs@ws ; fs = (ref xs)@wc + xc@ws = xc@ws - xs@wc
__global__ void mix_kernel(const float* __restrict__ xc, const float* __restrict__ xs,
                           const float* __restrict__ x0,
                           const float* __restrict__ wc, const float* __restrict__ wsp,
                           const float* __restrict__ w0, const float* __restrict__ ww,
                           const float* __restrict__ wbias, float* __restrict__ A, int layer) {
    int o = blockIdx.x, b = blockIdx.y;
    int k = threadIdx.x & 63, ig = threadIdx.x >> 6;
    const float* wcl = wc  + (long)layer * CC * CC * KK;
    const float* wsl = wsp + (long)layer * CC * CC * KK;
    float fc = 0.f, fs = 0.f;
    for (int i = ig * 32; i < ig * 32 + 32; ++i) {
        float xci = xc[(b * CC + i) * KK + k];
        float xsi = xs[(b * CC + i) * KK + k];
        float wcv = wcl[((long)i * CC + o) * KK + k];
        float wsv = wsl[((long)i * CC + o) * KK + k];
        fc += xci * wcv + xsi * wsv;
        fs += xci * wsv - xsi * wcv;
    }
    __shared__ float rc[4][64], rs[4][64];
    rc[ig][k] = fc;
    rs[ig][k] = fs;
    __syncthreads();
    long base = ((long)b * CC + o) * AR;
    if (ig == 0) {
        fc = rc[0][k] + rc[1][k] + rc[2][k] + rc[3][k];
        fs = rs[0][k] + rs[1][k] + rs[2][k] + rs[3][k];
        A[base + k]      = 2.f * fc;
        A[base + 64 + k] = -2.f * fs;
    } else if (ig == 1) {
        const float* wwl = ww + ((long)layer * CC + o) * CC;
        A[base + 128 + k] = wwl[k];
        A[base + 192 + k] = wwl[64 + k];
    } else if (ig == 2) {
        const float* w0l = w0 + (long)layer * CC * CC;
        float p = x0[b * CC + k] * w0l[(long)k * CC + o]
                + x0[b * CC + 64 + k] * w0l[(long)(64 + k) * CC + o];
        #pragma unroll
        for (int off = 32; off > 0; off >>= 1) p += __shfl_down(p, off, 64);
        if (k == 0) {
            A[base + 256] = p;                       // f0
            A[base + 257] = wbias[layer * CC + o];   // w_b
        }
    }
}

// ---------------- inverse + 1x1-conv fused GEMM: out = A @ [bc;bs;h] + f0*mask + w_b ----------------
// block tile [128 o][64 n], 128 threads, 8o x 8n per thread. grid (NCHUNK, BATCH)
template <int DOGELU, int DOTRANS>
__global__ __launch_bounds__(128) void inverse_kernel(
        const float* __restrict__ A, const float* __restrict__ bc, const float* __restrict__ bs,
        const float* __restrict__ hin, const float* __restrict__ mask, float* __restrict__ hout) {
    int nb = blockIdx.x, b = blockIdx.y;
    int n0 = nb * 64;
    int t = threadIdx.x;
    int to = t & 15, tn = t >> 4;      // to 0..15, tn 0..7
    __shared__ float As[16][128];
    __shared__ float Bs[16][72];
    float acc[8][8];
    #pragma unroll
    for (int j = 0; j < 8; ++j)
        #pragma unroll
        for (int q = 0; q < 8; ++q) acc[j][q] = 0.f;

    const float* bcb = bc + (long)b * KK * NN;
    const float* bsb = bs + (long)b * KK * NN;
    const float* hb  = hin + (long)b * CC * NN;
    const float* Ab  = A + (long)b * CC * AR;

    for (int ch = 0; ch < 16; ++ch) {
        int r0 = ch * 16;
        const float* src;
        int roff;
        if (ch < 4)      { src = bcb; roff = r0; }
        else if (ch < 8) { src = bsb; roff = r0 - 64; }
        else             { src = hb;  roff = r0 - 128; }
        __syncthreads();
        {
            const float* ar = Ab + (long)t * AR + r0;
            #pragma unroll
            for (int i = 0; i < 16; i += 4) {
                float4 v = *(const float4*)(ar + i);
                As[i][t] = v.x; As[i + 1][t] = v.y; As[i + 2][t] = v.z; As[i + 3][t] = v.w;
            }
        }
        {
            int r = t >> 3, cq = (t & 7) * 8;
            const float* br = src + (long)(roff + r) * NN + n0 + cq;
            float4 v0 = *(const float4*)br;
            float4 v1 = *(const float4*)(br + 4);
            *(float4*)&Bs[r][cq] = v0;
            *(float4*)&Bs[r][cq + 4] = v1;
        }
        __syncthreads();
        #pragma unroll
        for (int r = 0; r < 16; ++r) {
            float av[8], bv[8];
            #pragma unroll
            for (int j = 0; j < 8; ++j) av[j] = As[r][to + 16 * j];
            #pragma unroll
            for (int q = 0; q < 8; ++q) bv[q] = Bs[r][tn * 8 + q];
            #pragma unroll
            for (int j = 0; j < 8; ++j)
                #pragma unroll
                for (int q = 0; q < 8; ++q) acc[j][q] += av[j] * bv[q];
        }
    }
    float f0v[8], wbv[8];
    #pragma unroll
    for (int j = 0; j < 8; ++j) {
        const float* ar = Ab + (long)(to + 16 * j) * AR;
        f0v[j] = ar[256];
        wbv[j] = ar[257];
    }
    float mv[8];
    const float* mrow = mask + (long)b * NN + n0 + tn * 8;
    #pragma unroll
    for (int q = 0; q < 8; ++q) mv[q] = mrow[q];

    if constexpr (!DOTRANS) {
        #pragma unroll
        for (int j = 0; j < 8; ++j) {
            int o = to + 16 * j;
            float vals[8];
            #pragma unroll
            for (int q = 0; q < 8; ++q) {
                float v = acc[j][q] + f0v[j] * mv[q] + wbv[j];
                if (DOGELU) v = gelu_exact(v);
                vals[q] = v;
            }
            float* orow = hout + ((long)b * CC + o) * NN + n0 + tn * 8;
            *(float4*)orow = make_float4(vals[0], vals[1], vals[2], vals[3]);
            *(float4*)(orow + 4) = make_float4(vals[4], vals[5], vals[6], vals[7]);
        }
    } else {
        __shared__ float Ts[64][132];
        #pragma unroll
        for (int j = 0; j < 8; ++j)
            #pragma unroll
            for (int q = 0; q < 8; ++q)
                Ts[tn * 8 + q][to + 16 * j] = acc[j][q] + f0v[j] * mv[q] + wbv[j];
        __syncthreads();
        int row = t >> 1, half = t & 1;
        float* orow = hout + ((long)b * NN + n0 + row) * CC + half * 64;
        #pragma unroll
        for (int qq = 0; qq < 16; ++qq)
            *(float4*)(orow + qq * 4) = *(float4*)&Ts[row][half * 64 + qq * 4];
    }
}

// ---------------- head: out = gelu(hT @ fc1 + b1) @ fc2 + b2 ----------------
__global__ __launch_bounds__(256) void head_kernel(const float* __restrict__ hT,
        const float* __restrict__ w1, const float* __restrict__ b1,
        const float* __restrict__ w2, const float* __restrict__ b2,
        float* __restrict__ out) {
    __shared__ float hs[32][128];
    __shared__ float red[2][2][2];
    int t = threadIdx.x;
    long n0 = (long)blockIdx.x * 32;
    #pragma unroll
    for (int i = 0; i < 4; ++i) {
        int flat = (i * 256 + t) * 4;
        int row = flat >> 7, col = flat & 127;
        *(float4*)&hs[row][col] = *(const float4*)(hT + (n0 + row) * CC + col);
    }
    int f = t & 127, g = t >> 7;
    float w1r[128];
    #pragma unroll
    for (int c = 0; c < 128; ++c) w1r[c] = w1[c * 128 + f];
    float b1f = b1[f], w2f = w2[f], b2v = b2[0];
    __syncthreads();
    int wv = (t >> 6) & 1;
    #pragma unroll 1
    for (int jn = 0; jn < 16; ++jn) {
        int nl = g * 16 + jn;
        float acc = b1f;
        #pragma unroll
        for (int c = 0; c < 128; ++c) acc += hs[nl][c] * w1r[c];
        float pv = gelu_exact(acc) * w2f;
        #pragma unroll
        for (int off = 32; off > 0; off >>= 1) pv += __shfl_down(pv, off, 64);
        if ((t & 63) == 0) red[g][wv][jn & 1] = pv;
        __syncthreads();
        if (f == 0) out[n0 + nl] = red[g][0][jn & 1] + red[g][1][jn & 1] + b2v;
    }
}

extern "C" void kernel_launch(void* const* d_in, const int* in_sizes, int n_in,
                              void* d_out, int out_size, void* d_ws, size_t ws_size,
                              hipStream_t stream) {
    const float* x     = (const float*)d_in[0];
    const float* mask  = (const float*)d_in[1];
    const float* nodes = (const float*)d_in[2];
    const float* wts   = (const float*)d_in[3];
    // d_in[4], d_in[5]: directed_edges / edge_gradient_weights -- dead (x3 never added)
    const float* modes = (const float*)d_in[6];
    const float* fc0w  = (const float*)d_in[7];
    const float* fc0b  = (const float*)d_in[8];
    const float* spwc  = (const float*)d_in[9];
    const float* spws  = (const float*)d_in[10];
    const float* spw0  = (const float*)d_in[11];
    const float* ww    = (const float*)d_in[12];
    const float* wb    = (const float*)d_in[13];
    // d_in[14], d_in[15]: gw_w / gw_b -- dead
    const float* fc1w  = (const float*)d_in[16];
    const float* fc1b  = (const float*)d_in[17];
    const float* fc2w  = (const float*)d_in[18];
    const float* fc2b  = (const float*)d_in[19];

    float* ws  = (float*)d_ws;
    float* bc  = ws;
    float* bs  = bc + (long)BATCH * KK * NN;
    float* h0  = bs + (long)BATCH * KK * NN;
    float* h1  = h0 + (long)BATCH * CC * NN;
    float* pxc = h1 + (long)BATCH * CC * NN;
    float* pxs = pxc + (long)SPLITS * BATCH * CC * KK;
    float* px0 = pxs + (long)SPLITS * BATCH * CC * KK;
    float* xc  = px0 + (long)SPLITS * BATCH * CC;
    float* xs  = xc + BATCH * CC * KK;
    float* x0  = xs + BATCH * CC * KK;
    float* Ab  = x0 + BATCH * CC;

    basis_kernel<<<(BATCH * NN + 255) / 256, 256, 0, stream>>>(nodes, mask, modes, bc, bs);
    lift_kernel<<<(BATCH * CC * NN) / 256, 256, 0, stream>>>(x, fc0w, fc0b, h0);

    float* hbuf[2] = {h0, h1};
    int cur = 0;
    for (int l = 0; l < NLAYER; ++l) {
        forward_kernel<<<dim3(SPLITS, CC / 64, BATCH), 128, 0, stream>>>(
            hbuf[cur], bc, bs, wts, mask, pxc, pxs, px0);
        reduce_kernel<<<(BATCH * CC * KK + 255) / 256, 256, 0, stream>>>(pxc, pxs, px0, xc, xs, x0);
        mix_kernel<<<dim3(CC, BATCH), 256, 0, stream>>>(xc, xs, x0, spwc, spws, spw0, ww, wb, Ab, l);
        if (l < NLAYER - 1)
            inverse_kernel<1, 0><<<dim3(NCHUNK, BATCH), 128, 0, stream>>>(
                Ab, bc, bs, hbuf[cur], mask, hbuf[cur ^ 1]);
        else
            inverse_kernel<0, 1><<<dim3(NCHUNK, BATCH), 128, 0, stream>>>(
                Ab, bc, bs, hbuf[cur], mask, hbuf[cur ^ 1]);
        cur ^= 1;
    }
    head_kernel<<<(BATCH * NN) / 32, 256, 0, stream>>>(hbuf[cur], fc1w, fc1b, fc2w, fc2b, (float*)d_out);
}

// Round 2
// 449.330 us; speedup vs baseline: 2.1655x; 2.1655x over previous
//
#include <hip/hip_runtime.h>
#include <math.h>

#define NN 40000
#define NP 40064          // 313 * 128, padded node count
#define CC 128
#define KK 64
#define BATCH 2
#define NLAYER 4
#define FSPLITS 128
#define MODES 144         // 64 cos + 64 sin + 1 zero-mode + 15 zero pad
#define KTOT 256          // inverse GEMM contraction: 64 bc + 64 bs + 128 h

typedef __attribute__((ext_vector_type(8))) short bf16x8;
typedef __attribute__((ext_vector_type(4))) float f32x4;
typedef __attribute__((ext_vector_type(4))) unsigned short u16x4;
typedef __attribute__((ext_vector_type(8))) unsigned short u16x8;

__device__ __forceinline__ float gelu_exact(float x) {
    return 0.5f * x * (1.0f + erff(x * 0.70710678118654752f));
}
__device__ __forceinline__ unsigned short f2bf(float x) {   // RNE float->bf16
    unsigned int u = __float_as_uint(x);
    u += 0x7FFFu + ((u >> 16) & 1u);
    return (unsigned short)(u >> 16);
}

// ---------- basis: fills wbcs [B][144][NP] (bf16), Binv cols 0..127 (bf16), maskp ----------
__global__ __launch_bounds__(256) void basis_kernel(
        const float* __restrict__ nodes, const float* __restrict__ mask,
        const float* __restrict__ wts, const float* __restrict__ modes,
        unsigned short* __restrict__ wbcs, unsigned short* __restrict__ Binv,
        float* __restrict__ maskp) {
    __shared__ float sm[KK * 2];
    int t = threadIdx.x;
    if (t < KK * 2) sm[t] = modes[t];
    __syncthreads();
    int idx = blockIdx.x * 256 + t;          // over B*NP (exact)
    int b = idx / NP, n = idx - b * NP;
    float nx = 0.f, ny = 0.f, m = 0.f, w = 0.f;
    if (n < NN) {
        long gi = (long)b * NN + n;
        nx = nodes[gi * 2]; ny = nodes[gi * 2 + 1];
        m = mask[gi]; w = wts[gi];
    }
    float mw = m * w;
    unsigned short* wrow = wbcs + (long)b * MODES * NP + n;
    unsigned int bcp[32], bsp[32];
    #pragma unroll
    for (int k2 = 0; k2 < 32; ++k2) {
        float t0 = nx * sm[4 * k2]     + ny * sm[4 * k2 + 1];
        float t1 = nx * sm[4 * k2 + 2] + ny * sm[4 * k2 + 3];
        float s0, c0, s1, c1;
        __sincosf(t0, &s0, &c0);
        __sincosf(t1, &s1, &c1);
        int k0 = 2 * k2;
        wrow[(long)k0 * NP]            = f2bf(c0 * mw);
        wrow[(long)(k0 + 1) * NP]      = f2bf(c1 * mw);
        wrow[(long)(64 + k0) * NP]     = f2bf(s0 * mw);
        wrow[(long)(64 + k0 + 1) * NP] = f2bf(s1 * mw);
        bcp[k2] = (unsigned int)f2bf(c0 * m) | ((unsigned int)f2bf(c1 * m) << 16);
        bsp[k2] = (unsigned int)f2bf(s0 * m) | ((unsigned int)f2bf(s1 * m) << 16);
    }
    wrow[(long)128 * NP] = f2bf(mw);
    #pragma unroll
    for (int r = 129; r < MODES; ++r) wrow[(long)r * NP] = 0;
    maskp[idx] = m;
    uint4* brow = (uint4*)(Binv + (long)idx * KTOT);
    #pragma unroll
    for (int q = 0; q < 8; ++q)
        brow[q] = make_uint4(bcp[4*q], bcp[4*q+1], bcp[4*q+2], bcp[4*q+3]);
    #pragma unroll
    for (int q = 0; q < 8; ++q)
        brow[8 + q] = make_uint4(bsp[4*q], bsp[4*q+1], bsp[4*q+2], bsp[4*q+3]);
}

// ---------- lift into Binv h-region: h = x@fc0_w + b ----------
__global__ __launch_bounds__(256) void lift_binv(const float* __restrict__ x,
        const float* __restrict__ w, const float* __restrict__ bvec,
        unsigned short* __restrict__ Binv) {
    int t = threadIdx.x;
    int c = t & 127;
    int gi = blockIdx.x * 2 + (t >> 7);      // over B*NP
    int b = gi / NP, n = gi - b * NP;
    float h = 0.f;
    if (n < NN) {
        const float* xr = x + ((long)b * NN + n) * 3;
        h = bvec[c] + xr[0] * w[c] + xr[1] * w[CC + c] + xr[2] * w[2 * CC + c];
    }
    Binv[(long)gi * KTOT + 128 + c] = f2bf(h);
}

// ---------- lift into hcn [B][C][NP] ----------
__global__ __launch_bounds__(256) void lift_hcn(const float* __restrict__ x,
        const float* __restrict__ w, const float* __restrict__ bvec,
        unsigned short* __restrict__ hcn) {
    int id = blockIdx.x * 256 + threadIdx.x;     // B*CC*NP/8 exact
    int n8 = NP / 8;
    int nb = (id % n8) * 8;
    int c  = (id / n8) % CC;
    int b  = id / (n8 * CC);
    float w0 = w[c], w1 = w[CC + c], w2 = w[2 * CC + c], bv = bvec[c];
    u16x8 hv;
    #pragma unroll
    for (int i = 0; i < 8; ++i) {
        int n = nb + i;
        float h = 0.f;
        if (n < NN) {
            const float* xr = x + ((long)b * NN + n) * 3;
            h = bv + xr[0] * w0 + xr[1] * w1 + xr[2] * w2;
        }
        hv[i] = f2bf(h);
    }
    *(u16x8*)(hcn + ((long)b * CC + c) * NP + nb) = hv;
}

// ---------- fc1 transpose to [f][c] bf16 ----------
__global__ void fc1t_kernel(const float* __restrict__ fc1, unsigned short* __restrict__ fc1t) {
    int idx = blockIdx.x * 256 + threadIdx.x;    // 16384
    int f = idx >> 7, c = idx & 127;
    fc1t[f * 128 + c] = f2bf(fc1[c * 128 + f]);
}

// ---------- forward transform MFMA: pxcs[s][b][c][mode] += h[c][n]*wbcs[mode][n] ----------
__global__ __launch_bounds__(512) void forward_mfma(const unsigned short* __restrict__ hcn,
        const unsigned short* __restrict__ wbcs, float* __restrict__ pxcs) {
    int s = blockIdx.x, b = blockIdx.y;
    int t = threadIdx.x, wv = t >> 6, l = t & 63, lo = l & 15, hi = l >> 4;
    const unsigned short* ab  = hcn  + ((long)b * CC + wv * 16 + lo) * NP + hi * 8;
    const unsigned short* bb0 = wbcs + ((long)b * MODES + lo) * NP + hi * 8;
    f32x4 acc[9];
    #pragma unroll
    for (int mt = 0; mt < 9; ++mt) acc[mt] = (f32x4){0.f, 0.f, 0.f, 0.f};
    for (int chunk = s; chunk < NP / 32; chunk += FSPLITS) {
        int kb = chunk * 32;
        bf16x8 a = *(const bf16x8*)(ab + kb);
        #pragma unroll
        for (int mt = 0; mt < 9; ++mt) {
            bf16x8 bv = *(const bf16x8*)(bb0 + (long)mt * 16 * NP + kb);
            acc[mt] = __builtin_amdgcn_mfma_f32_16x16x32_bf16(a, bv, acc[mt], 0, 0, 0);
        }
    }
    float* pb = pxcs + ((long)s * BATCH + b) * CC * MODES;
    #pragma unroll
    for (int mt = 0; mt < 9; ++mt) {
        int mcol = mt * 16 + lo;
        #pragma unroll
        for (int r = 0; r < 4; ++r) {
            int crow = wv * 16 + hi * 4 + r;
            pb[(long)crow * MODES + mcol] = acc[mt][r];
        }
    }
}

// ---------- reduce split partials -> xc, xs, x0 ----------
__global__ void reduce_kernel(const float* __restrict__ pxcs, float* __restrict__ xc,
                              float* __restrict__ xs, float* __restrict__ x0) {
    int idx = blockIdx.x * 256 + threadIdx.x;    // B*CC*MODES = 36864 exact
    int m = idx % MODES, bc_ = idx / MODES;
    float a = 0.f;
    for (int s = 0; s < FSPLITS; ++s) a += pxcs[(long)s * BATCH * CC * MODES + idx];
    if (m < 64)        xc[bc_ * KK + m] = a;
    else if (m < 128)  xs[bc_ * KK + m - 64] = a;
    else if (m == 128) x0[bc_] = a;
}

// ---------- mix: assemble A=[2fc|-2fs|ww] bf16, f0/wb fp32 ----------
__global__ __launch_bounds__(256) void mix_kernel(const float* __restrict__ xc,
        const float* __restrict__ xs, const float* __restrict__ x0,
        const float* __restrict__ wc, const float* __restrict__ wsp,
        const float* __restrict__ w0, const float* __restrict__ ww,
        const float* __restrict__ wbias, unsigned short* __restrict__ A,
        float* __restrict__ f0a, float* __restrict__ wba, int layer) {
    int o = blockIdx.x, b = blockIdx.y;
    int k = threadIdx.x & 63, ig = threadIdx.x >> 6;
    const float* wcl = wc  + (long)layer * CC * CC * KK;
    const float* wsl = wsp + (long)layer * CC * CC * KK;
    float fc = 0.f, fs = 0.f;
    for (int i = ig * 32; i < ig * 32 + 32; ++i) {
        float xci = xc[(b * CC + i) * KK + k];
        float xsi = xs[(b * CC + i) * KK + k];
        float wcv = wcl[((long)i * CC + o) * KK + k];
        float wsv = wsl[((long)i * CC + o) * KK + k];
        fc += xci * wcv + xsi * wsv;
        fs += xci * wsv - xsi * wcv;
    }
    __shared__ float rc[4][64], rs[4][64];
    rc[ig][k] = fc; rs[ig][k] = fs;
    __syncthreads();
    unsigned short* Ar = A + ((long)b * CC + o) * KTOT;
    if (ig == 0) {
        fc = rc[0][k] + rc[1][k] + rc[2][k] + rc[3][k];
        fs = rs[0][k] + rs[1][k] + rs[2][k] + rs[3][k];
        Ar[k]      = f2bf(2.f * fc);
        Ar[64 + k] = f2bf(-2.f * fs);
    } else if (ig == 1) {
        const float* wwl = ww + ((long)layer * CC + o) * CC;
        Ar[128 + k] = f2bf(wwl[k]);
        Ar[192 + k] = f2bf(wwl[64 + k]);
    } else if (ig == 2) {
        const float* w0l = w0 + (long)layer * CC * CC;
        float p = x0[b * CC + k] * w0l[(long)k * CC + o]
                + x0[b * CC + 64 + k] * w0l[(long)(64 + k) * CC + o];
        #pragma unroll
        for (int off = 32; off > 0; off >>= 1) p += __shfl_down(p, off, 64);
        if (k == 0) { f0a[b * CC + o] = p; wba[b * CC + o] = wbias[layer * CC + o]; }
    }
}

// ---------- inverse + 1x1 conv MFMA: out = A@[bc;bs;h] + f0*mask + wb ----------
// 8 waves = 4 o-groups x 2 n-groups; wave tile 32o x 64n; A in regs, B direct global.
template <int DOGELU, int WRITE_HCN>
__global__ __launch_bounds__(512) void inverse_mfma(const unsigned short* __restrict__ Amat,
        unsigned short* Binv, const float* __restrict__ f0a, const float* __restrict__ wba,
        const float* __restrict__ maskp, unsigned short* __restrict__ hcn) {
    int nt = blockIdx.x, b = blockIdx.y;
    int t = threadIdx.x, wv = t >> 6, l = t & 63, lo = l & 15, hi = l >> 4;
    int wr = wv >> 1, wn = wv & 1;
    int obase = wr * 32;
    int nbase = nt * 128 + wn * 64;
    const unsigned short* Ab = Amat + (long)b * CC * KTOT;
    bf16x8 af[2][8];
    #pragma unroll
    for (int fr = 0; fr < 2; ++fr) {
        const unsigned short* arow = Ab + (long)(obase + fr * 16 + lo) * KTOT + hi * 8;
        #pragma unroll
        for (int ks = 0; ks < 8; ++ks) af[fr][ks] = *(const bf16x8*)(arow + ks * 32);
    }
    f32x4 acc[2][4];
    #pragma unroll
    for (int fr = 0; fr < 2; ++fr)
        #pragma unroll
        for (int fn = 0; fn < 4; ++fn) acc[fr][fn] = (f32x4){0.f, 0.f, 0.f, 0.f};
    const unsigned short* Bb = Binv + (long)b * NP * KTOT;
    #pragma unroll
    for (int ks = 0; ks < 8; ++ks) {
        #pragma unroll
        for (int fn = 0; fn < 4; ++fn) {
            const unsigned short* brow = Bb + (long)(nbase + fn * 16 + lo) * KTOT + ks * 32 + hi * 8;
            bf16x8 bv = *(const bf16x8*)brow;
            acc[0][fn] = __builtin_amdgcn_mfma_f32_16x16x32_bf16(af[0][ks], bv, acc[0][fn], 0, 0, 0);
            acc[1][fn] = __builtin_amdgcn_mfma_f32_16x16x32_bf16(af[1][ks], bv, acc[1][fn], 0, 0, 0);
        }
    }
    __syncthreads();   // all reads of old h done before any wave overwrites (in-place update)
    #pragma unroll
    for (int fr = 0; fr < 2; ++fr) {
        int o0 = obase + fr * 16 + hi * 4;
        f32x4 f0v = *(const f32x4*)(f0a + b * CC + o0);
        f32x4 wbv = *(const f32x4*)(wba + b * CC + o0);
        #pragma unroll
        for (int fn = 0; fn < 4; ++fn) {
            int n = nbase + fn * 16 + lo;
            float mv = maskp[b * NP + n];
            u16x4 pk;
            #pragma unroll
            for (int r = 0; r < 4; ++r) {
                float v = acc[fr][fn][r] + f0v[r] * mv + wbv[r];
                if (DOGELU) v = gelu_exact(v);
                pk[r] = f2bf(v);
                if (WRITE_HCN) hcn[((long)b * CC + o0 + r) * NP + n] = pk[r];
            }
            *(u16x4*)(Binv + ((long)b * NP + n) * KTOT + 128 + o0) = pk;
        }
    }
}

// ---------- head: out = gelu(hT@fc1 + b1) @ fc2 + b2 (MFMA stage1 + VALU stage2) ----------
__global__ __launch_bounds__(256) void head_mfma(const unsigned short* __restrict__ Binv,
        const unsigned short* __restrict__ fc1t, const float* __restrict__ b1,
        const float* __restrict__ fc2, const float* __restrict__ b2, float* __restrict__ out) {
    int t = threadIdx.x, wv = t >> 6, l = t & 63, lo = l & 15, hi = l >> 4;
    int b = blockIdx.y;
    int nb = (blockIdx.x * 4 + wv) * 16;
    const unsigned short* Arow = Binv + ((long)b * NP + nb + lo) * KTOT + 128 + hi * 8;
    f32x4 acc[8];
    #pragma unroll
    for (int ft = 0; ft < 8; ++ft) acc[ft] = (f32x4){0.f, 0.f, 0.f, 0.f};
    #pragma unroll
    for (int ks = 0; ks < 4; ++ks) {
        bf16x8 a = *(const bf16x8*)(Arow + ks * 32);
        #pragma unroll
        for (int ft = 0; ft < 8; ++ft) {
            bf16x8 bv = *(const bf16x8*)(fc1t + (ft * 16 + lo) * 128 + ks * 32 + hi * 8);
            acc[ft] = __builtin_amdgcn_mfma_f32_16x16x32_bf16(a, bv, acc[ft], 0, 0, 0);
        }
    }
    float s[4] = {0.f, 0.f, 0.f, 0.f};
    #pragma unroll
    for (int ft = 0; ft < 8; ++ft) {
        int f = ft * 16 + lo;
        float b1f = b1[f], f2f = fc2[f];
        #pragma unroll
        for (int r = 0; r < 4; ++r) s[r] += gelu_exact(acc[ft][r] + b1f) * f2f;
    }
    float b2v = b2[0];
    #pragma unroll
    for (int r = 0; r < 4; ++r) {
        float v = s[r];
        v += __shfl_xor(v, 1); v += __shfl_xor(v, 2);
        v += __shfl_xor(v, 4); v += __shfl_xor(v, 8);
        if (lo == 0) out[(long)b * NN + nb + hi * 4 + r] = v + b2v;
    }
}

extern "C" void kernel_launch(void* const* d_in, const int* in_sizes, int n_in,
                              void* d_out, int out_size, void* d_ws, size_t ws_size,
                              hipStream_t stream) {
    const float* x     = (const float*)d_in[0];
    const float* mask  = (const float*)d_in[1];
    const float* nodes = (const float*)d_in[2];
    const float* wts   = (const float*)d_in[3];
    // d_in[4] directed_edges, d_in[5] edge_gradient_weights: dead (x3 never added)
    const float* modes = (const float*)d_in[6];
    const float* fc0w  = (const float*)d_in[7];
    const float* fc0b  = (const float*)d_in[8];
    const float* spwc  = (const float*)d_in[9];
    const float* spws  = (const float*)d_in[10];
    const float* spw0  = (const float*)d_in[11];
    const float* ww    = (const float*)d_in[12];
    const float* wb    = (const float*)d_in[13];
    // d_in[14] gw_w, d_in[15] gw_b: dead
    const float* fc1w  = (const float*)d_in[16];
    const float* fc1b  = (const float*)d_in[17];
    const float* fc2w  = (const float*)d_in[18];
    const float* fc2b  = (const float*)d_in[19];

    char* p = (char*)d_ws;
    auto alloc = [&](size_t bytes) { char* r = p; p += (bytes + 255) & ~255UL; return r; };
    unsigned short* Binv = (unsigned short*)alloc((size_t)BATCH * NP * KTOT * 2);
    unsigned short* wbcs = (unsigned short*)alloc((size_t)BATCH * MODES * NP * 2);
    unsigned short* hcn  = (unsigned short*)alloc((size_t)BATCH * CC * NP * 2);
    unsigned short* Amat = (unsigned short*)alloc((size_t)BATCH * CC * KTOT * 2);
    unsigned short* fc1t = (unsigned short*)alloc((size_t)CC * 128 * 2);
    float* pxcs = (float*)alloc((size_t)FSPLITS * BATCH * CC * MODES * 4);
    float* xcb  = (float*)alloc((size_t)BATCH * CC * KK * 4);
    float* xsb  = (float*)alloc((size_t)BATCH * CC * KK * 4);
    float* x0b  = (float*)alloc((size_t)BATCH * CC * 4);
    float* f0a  = (float*)alloc((size_t)BATCH * CC * 4);
    float* wba  = (float*)alloc((size_t)BATCH * CC * 4);
    float* maskp = (float*)alloc((size_t)BATCH * NP * 4);

    basis_kernel<<<(BATCH * NP) / 256, 256, 0, stream>>>(nodes, mask, wts, modes, wbcs, Binv, maskp);
    lift_binv<<<(BATCH * NP) / 2, 256, 0, stream>>>(x, fc0w, fc0b, Binv);
    lift_hcn<<<(BATCH * CC * NP / 8) / 256, 256, 0, stream>>>(x, fc0w, fc0b, hcn);
    fc1t_kernel<<<64, 256, 0, stream>>>(fc1w, fc1t);

    for (int l = 0; l < NLAYER; ++l) {
        forward_mfma<<<dim3(FSPLITS, BATCH), 512, 0, stream>>>(hcn, wbcs, pxcs);
        reduce_kernel<<<(BATCH * CC * MODES) / 256, 256, 0, stream>>>(pxcs, xcb, xsb, x0b);
        mix_kernel<<<dim3(CC, BATCH), 256, 0, stream>>>(xcb, xsb, x0b, spwc, spws, spw0,
                                                        ww, wb, Amat, f0a, wba, l);
        if (l < NLAYER - 1)
            inverse_mfma<1, 1><<<dim3(NP / 128, BATCH), 512, 0, stream>>>(
                Amat, Binv, f0a, wba, maskp, hcn);
        else
            inverse_mfma<0, 0><<<dim3(NP / 128, BATCH), 512, 0, stream>>>(
                Amat, Binv, f0a, wba, maskp, hcn);
    }
    head_mfma<<<dim3(NN / 64, BATCH), 256, 0, stream>>>(Binv, fc1t, fc1b, fc2w, fc2b, (float*)d_out);
}

// Round 3
// 350.303 us; speedup vs baseline: 2.7777x; 1.2827x over previous
//
#include <hip/hip_runtime.h>
#include <math.h>

#define NN 40000
#define NP 40064          // 313 * 128, padded node count
#define CC 128
#define KK 64
#define BATCH 2
#define NLAYER 4
#define FSPLITS 128
#define MODES 144         // 64 cos + 64 sin + 1 zero-mode + 15 zero pad
#define KTOT 256          // inverse GEMM contraction: 64 bc + 64 bs + 128 h

typedef __attribute__((ext_vector_type(8))) short bf16x8;
typedef __attribute__((ext_vector_type(4))) float f32x4;
typedef __attribute__((ext_vector_type(4))) unsigned short u16x4;
typedef __attribute__((ext_vector_type(8))) unsigned short u16x8;

__device__ __forceinline__ float gelu_exact(float x) {
    return 0.5f * x * (1.0f + erff(x * 0.70710678118654752f));
}
__device__ __forceinline__ unsigned short f2bf(float x) {   // RNE float->bf16
    unsigned int u = __float_as_uint(x);
    u += 0x7FFFu + ((u >> 16) & 1u);
    return (unsigned short)(u >> 16);
}

// ---------- basis: fills wbcs [B][144][NP] (bf16), Binv cols 0..127 (bf16), maskp ----------
__global__ __launch_bounds__(256) void basis_kernel(
        const float* __restrict__ nodes, const float* __restrict__ mask,
        const float* __restrict__ wts, const float* __restrict__ modes,
        unsigned short* __restrict__ wbcs, unsigned short* __restrict__ Binv,
        float* __restrict__ maskp) {
    __shared__ float sm[KK * 2];
    int t = threadIdx.x;
    if (t < KK * 2) sm[t] = modes[t];
    __syncthreads();
    int idx = blockIdx.x * 256 + t;          // over B*NP (exact)
    int b = idx / NP, n = idx - b * NP;
    float nx = 0.f, ny = 0.f, m = 0.f, w = 0.f;
    if (n < NN) {
        long gi = (long)b * NN + n;
        nx = nodes[gi * 2]; ny = nodes[gi * 2 + 1];
        m = mask[gi]; w = wts[gi];
    }
    float mw = m * w;
    unsigned short* wrow = wbcs + (long)b * MODES * NP + n;
    unsigned int bcp[32], bsp[32];
    #pragma unroll
    for (int k2 = 0; k2 < 32; ++k2) {
        float t0 = nx * sm[4 * k2]     + ny * sm[4 * k2 + 1];
        float t1 = nx * sm[4 * k2 + 2] + ny * sm[4 * k2 + 3];
        float s0, c0, s1, c1;
        __sincosf(t0, &s0, &c0);
        __sincosf(t1, &s1, &c1);
        int k0 = 2 * k2;
        wrow[(long)k0 * NP]            = f2bf(c0 * mw);
        wrow[(long)(k0 + 1) * NP]      = f2bf(c1 * mw);
        wrow[(long)(64 + k0) * NP]     = f2bf(s0 * mw);
        wrow[(long)(64 + k0 + 1) * NP] = f2bf(s1 * mw);
        bcp[k2] = (unsigned int)f2bf(c0 * m) | ((unsigned int)f2bf(c1 * m) << 16);
        bsp[k2] = (unsigned int)f2bf(s0 * m) | ((unsigned int)f2bf(s1 * m) << 16);
    }
    wrow[(long)128 * NP] = f2bf(mw);
    #pragma unroll
    for (int r = 129; r < MODES; ++r) wrow[(long)r * NP] = 0;
    maskp[idx] = m;
    uint4* brow = (uint4*)(Binv + (long)idx * KTOT);
    #pragma unroll
    for (int q = 0; q < 8; ++q)
        brow[q] = make_uint4(bcp[4*q], bcp[4*q+1], bcp[4*q+2], bcp[4*q+3]);
    #pragma unroll
    for (int q = 0; q < 8; ++q)
        brow[8 + q] = make_uint4(bsp[4*q], bsp[4*q+1], bsp[4*q+2], bsp[4*q+3]);
}

// ---------- lift into Binv h-region ----------
__global__ __launch_bounds__(256) void lift_binv(const float* __restrict__ x,
        const float* __restrict__ w, const float* __restrict__ bvec,
        unsigned short* __restrict__ Binv) {
    int t = threadIdx.x;
    int c = t & 127;
    int gi = blockIdx.x * 2 + (t >> 7);      // over B*NP
    int b = gi / NP, n = gi - b * NP;
    float h = 0.f;
    if (n < NN) {
        const float* xr = x + ((long)b * NN + n) * 3;
        h = bvec[c] + xr[0] * w[c] + xr[1] * w[CC + c] + xr[2] * w[2 * CC + c];
    }
    Binv[(long)gi * KTOT + 128 + c] = f2bf(h);
}

// ---------- lift into hcn [B][C][NP] ----------
__global__ __launch_bounds__(256) void lift_hcn(const float* __restrict__ x,
        const float* __restrict__ w, const float* __restrict__ bvec,
        unsigned short* __restrict__ hcn) {
    int id = blockIdx.x * 256 + threadIdx.x;     // B*CC*NP/8 exact
    int n8 = NP / 8;
    int nb = (id % n8) * 8;
    int c  = (id / n8) % CC;
    int b  = id / (n8 * CC);
    float w0 = w[c], w1 = w[CC + c], w2 = w[2 * CC + c], bv = bvec[c];
    u16x8 hv;
    #pragma unroll
    for (int i = 0; i < 8; ++i) {
        int n = nb + i;
        float h = 0.f;
        if (n < NN) {
            const float* xr = x + ((long)b * NN + n) * 3;
            h = bv + xr[0] * w0 + xr[1] * w1 + xr[2] * w2;
        }
        hv[i] = f2bf(h);
    }
    *(u16x8*)(hcn + ((long)b * CC + c) * NP + nb) = hv;
}

// ---------- fc1 transpose to [f][c] bf16 ----------
__global__ void fc1t_kernel(const float* __restrict__ fc1, unsigned short* __restrict__ fc1t) {
    int idx = blockIdx.x * 256 + threadIdx.x;    // 16384
    int f = idx >> 7, c = idx & 127;
    fc1t[f * 128 + c] = f2bf(fc1[c * 128 + f]);
}

// ---------- forward transform MFMA (LDS-staged): pxcs[s][b][c][mode] ----------
// grid (FSPLITS, 2, BATCH), 256 threads = 4 waves; block owns a 64-c half.
__global__ __launch_bounds__(256) void forward_mfma(const unsigned short* __restrict__ hcn,
        const unsigned short* __restrict__ wbcs, float* __restrict__ pxcs) {
    int s = blockIdx.x, ch = blockIdx.y, b = blockIdx.z;
    int t = threadIdx.x, wv = t >> 6, l = t & 63, lo = l & 15, hi = l >> 4;
    __shared__ __align__(16) char flds[8192 + 18432];   // h[64][128B] + wbcs[144][128B]
    int swz = (lo & 7) << 4;
    f32x4 acc[9];
    #pragma unroll
    for (int mt = 0; mt < 9; ++mt) acc[mt] = (f32x4){0.f, 0.f, 0.f, 0.f};
    const char* hbase = (const char*)(hcn + ((long)b * CC + ch * 64) * NP);
    const char* wbase = (const char*)(wbcs + (long)b * MODES * NP);

    for (int chunk = s; chunk < NP / 64; chunk += FSPLITS) {
        long n0b = (long)chunk * 128;           // byte offset of n0 within a row
        __syncthreads();
        #pragma unroll
        for (int i = 0; i < 2; ++i) {           // h tile: 8192B
            int off = i * 4096 + t * 16;
            int row = off >> 7, col = off & 127;
            uint4 v = *(const uint4*)(hbase + (long)row * (NP * 2) + n0b + col);
            *(uint4*)(flds + (off ^ ((row & 7) << 4))) = v;
        }
        #pragma unroll
        for (int j = 0; j < 5; ++j) {           // wbcs tile: 18432B
            if (j < 4 || t < 128) {
                int off = j * 4096 + t * 16;
                int row = off >> 7, col = off & 127;
                uint4 v = *(const uint4*)(wbase + (long)row * (NP * 2) + n0b + col);
                *(uint4*)(flds + 8192 + (off ^ ((row & 7) << 4))) = v;
            }
        }
        __syncthreads();
        int cg = wv * 16;
        bf16x8 a0 = *(const bf16x8*)(flds + (((cg + lo) * 128 + hi * 16) ^ swz));
        bf16x8 a1 = *(const bf16x8*)(flds + (((cg + lo) * 128 + 64 + hi * 16) ^ swz));
        #pragma unroll
        for (int mt = 0; mt < 9; ++mt) {
            int brow = mt * 16 + lo;
            bf16x8 b0 = *(const bf16x8*)(flds + 8192 + ((brow * 128 + hi * 16) ^ swz));
            bf16x8 b1 = *(const bf16x8*)(flds + 8192 + ((brow * 128 + 64 + hi * 16) ^ swz));
            acc[mt] = __builtin_amdgcn_mfma_f32_16x16x32_bf16(a0, b0, acc[mt], 0, 0, 0);
            acc[mt] = __builtin_amdgcn_mfma_f32_16x16x32_bf16(a1, b1, acc[mt], 0, 0, 0);
        }
    }
    float* pb = pxcs + ((long)s * BATCH + b) * CC * MODES;
    #pragma unroll
    for (int mt = 0; mt < 9; ++mt) {
        int mcol = mt * 16 + lo;
        #pragma unroll
        for (int r = 0; r < 4; ++r) {
            int crow = ch * 64 + wv * 16 + hi * 4 + r;
            pb[(long)crow * MODES + mcol] = acc[mt][r];
        }
    }
}

// ---------- reduce split partials -> xc, xs, x0 ----------
__global__ void reduce_kernel(const float* __restrict__ pxcs, float* __restrict__ xc,
                              float* __restrict__ xs, float* __restrict__ x0) {
    int idx = blockIdx.x * 256 + threadIdx.x;    // B*CC*MODES = 36864 exact
    int m = idx % MODES, bc_ = idx / MODES;
    float a = 0.f;
    for (int s = 0; s < FSPLITS; ++s) a += pxcs[(long)s * BATCH * CC * MODES + idx];
    if (m < 64)        xc[bc_ * KK + m] = a;
    else if (m < 128)  xs[bc_ * KK + m - 64] = a;
    else if (m == 128) x0[bc_] = a;
}

// ---------- mix: assemble A=[2fc|-2fs|ww] bf16, f0/wb fp32 ----------
__global__ __launch_bounds__(256) void mix_kernel(const float* __restrict__ xc,
        const float* __restrict__ xs, const float* __restrict__ x0,
        const float* __restrict__ wc, const float* __restrict__ wsp,
        const float* __restrict__ w0, const float* __restrict__ ww,
        const float* __restrict__ wbias, unsigned short* __restrict__ A,
        float* __restrict__ f0a, float* __restrict__ wba, int layer) {
    int o = blockIdx.x, b = blockIdx.y;
    int k = threadIdx.x & 63, ig = threadIdx.x >> 6;
    const float* wcl = wc  + (long)layer * CC * CC * KK;
    const float* wsl = wsp + (long)layer * CC * CC * KK;
    float fc = 0.f, fs = 0.f;
    for (int i = ig * 32; i < ig * 32 + 32; ++i) {
        float xci = xc[(b * CC + i) * KK + k];
        float xsi = xs[(b * CC + i) * KK + k];
        float wcv = wcl[((long)i * CC + o) * KK + k];
        float wsv = wsl[((long)i * CC + o) * KK + k];
        fc += xci * wcv + xsi * wsv;
        fs += xci * wsv - xsi * wcv;
    }
    __shared__ float rc[4][64], rs[4][64];
    rc[ig][k] = fc; rs[ig][k] = fs;
    __syncthreads();
    unsigned short* Ar = A + ((long)b * CC + o) * KTOT;
    if (ig == 0) {
        fc = rc[0][k] + rc[1][k] + rc[2][k] + rc[3][k];
        fs = rs[0][k] + rs[1][k] + rs[2][k] + rs[3][k];
        Ar[k]      = f2bf(2.f * fc);
        Ar[64 + k] = f2bf(-2.f * fs);
    } else if (ig == 1) {
        const float* wwl = ww + ((long)layer * CC + o) * CC;
        Ar[128 + k] = f2bf(wwl[k]);
        Ar[192 + k] = f2bf(wwl[64 + k]);
    } else if (ig == 2) {
        const float* w0l = w0 + (long)layer * CC * CC;
        float p = x0[b * CC + k] * w0l[(long)k * CC + o]
                + x0[b * CC + 64 + k] * w0l[(long)(64 + k) * CC + o];
        #pragma unroll
        for (int off = 32; off > 0; off >>= 1) p += __shfl_down(p, off, 64);
        if (k == 0) { f0a[b * CC + o] = p; wba[b * CC + o] = wbias[layer * CC + o]; }
    }
}

// ---------- inverse + 1x1 conv MFMA (LDS-staged, coalesced I/O) ----------
// grid (NP/64, BATCH), 256 threads = 4 waves; wave tile 32o x 64n.
template <int DOGELU, int WRITE_HCN>
__global__ __launch_bounds__(256) void inverse_mfma(const unsigned short* __restrict__ Amat,
        unsigned short* Binv, const float* __restrict__ f0a, const float* __restrict__ wba,
        const float* __restrict__ maskp, unsigned short* __restrict__ hcn) {
    int nt = blockIdx.x, b = blockIdx.y;
    int nbase = nt * 64;
    int t = threadIdx.x, wv = t >> 6, l = t & 63, lo = l & 15, hi = l >> 4;
    int obase = wv * 32;
    int swz = (lo & 7) << 4;
    __shared__ __align__(16) char lds_raw[34816];   // B-tile 32KB, then Ts 16KB + Ts2 18KB

    // A fragments (64KB matrix, L2-resident), loaded once
    const unsigned short* Ab = Amat + (long)b * CC * KTOT;
    bf16x8 af[2][8];
    #pragma unroll
    for (int fr = 0; fr < 2; ++fr) {
        const unsigned short* arow = Ab + (long)(obase + fr * 16 + lo) * KTOT + hi * 8;
        #pragma unroll
        for (int ks = 0; ks < 8; ++ks) af[fr][ks] = *(const bf16x8*)(arow + ks * 32);
    }
    // stage B-tile: contiguous 32KB -> swizzled LDS
    const char* Bsrc = (const char*)Binv + ((long)b * NP + nbase) * (KTOT * 2);
    #pragma unroll
    for (int i = 0; i < 8; ++i) {
        int off = i * 4096 + t * 16;
        int row = off >> 9;
        uint4 v = *(const uint4*)(Bsrc + off);
        *(uint4*)(lds_raw + (off ^ ((row & 7) << 4))) = v;
    }
    f32x4 acc[2][4];
    #pragma unroll
    for (int fr = 0; fr < 2; ++fr)
        #pragma unroll
        for (int fn = 0; fn < 4; ++fn) acc[fr][fn] = (f32x4){0.f, 0.f, 0.f, 0.f};
    __syncthreads();
    #pragma unroll
    for (int ks = 0; ks < 8; ++ks) {
        #pragma unroll
        for (int fn = 0; fn < 4; ++fn) {
            int boff = ((fn * 16 + lo) << 9) + (ks << 6) + (hi << 4);
            bf16x8 bv = *(const bf16x8*)(lds_raw + (boff ^ swz));
            acc[0][fn] = __builtin_amdgcn_mfma_f32_16x16x32_bf16(af[0][ks], bv, acc[0][fn], 0, 0, 0);
            acc[1][fn] = __builtin_amdgcn_mfma_f32_16x16x32_bf16(af[1][ks], bv, acc[1][fn], 0, 0, 0);
        }
    }
    __syncthreads();   // B-tile reads done; LDS reused for output transpose
    char* Ts  = lds_raw;            // [64 n][128 o] u16, row 256B, swizzled
    char* Ts2 = lds_raw + 16384;    // [128 o][72 u16], row 144B
    #pragma unroll
    for (int fr = 0; fr < 2; ++fr) {
        int o0 = obase + fr * 16 + hi * 4;
        f32x4 f0v = *(const f32x4*)(f0a + b * CC + o0);
        f32x4 wbv = *(const f32x4*)(wba + b * CC + o0);
        #pragma unroll
        for (int fn = 0; fn < 4; ++fn) {
            int n = fn * 16 + lo;
            float mv = maskp[(long)b * NP + nbase + n];
            u16x4 pk;
            #pragma unroll
            for (int r = 0; r < 4; ++r) {
                float v = acc[fr][fn][r] + f0v[r] * mv + wbv[r];
                if (DOGELU) v = gelu_exact(v);
                pk[r] = f2bf(v);
                if (WRITE_HCN) *(unsigned short*)(Ts2 + (o0 + r) * 144 + n * 2) = pk[r];
            }
            *(u16x4*)(Ts + (((n << 8) + (o0 << 1)) ^ ((n & 7) << 4))) = pk;
        }
    }
    __syncthreads();
    // Binv h-region: coalesced 16B stores, 4 rows x 256B per wave-pass
    char* Bdst = (char*)Binv + ((long)b * NP + nbase) * (KTOT * 2) + 256;
    #pragma unroll
    for (int pass = 0; pass < 4; ++pass) {
        int n = pass * 16 + (t >> 4);
        int chunk = t & 15;
        uint4 v = *(const uint4*)(Ts + (((n << 8) + (chunk << 4)) ^ ((n & 7) << 4)));
        *(uint4*)(Bdst + (long)n * 512 + chunk * 16) = v;
    }
    if (WRITE_HCN) {
        #pragma unroll
        for (int pass = 0; pass < 4; ++pass) {
            int o = pass * 32 + (t >> 3);
            int chunk = t & 7;
            uint4 v = *(const uint4*)(Ts2 + o * 144 + chunk * 16);
            *(uint4*)((char*)hcn + (((long)b * CC + o) * NP + nbase) * 2 + chunk * 16) = v;
        }
    }
}

// ---------- head: out = gelu(hT@fc1 + b1) @ fc2 + b2 ----------
__global__ __launch_bounds__(256) void head_mfma(const unsigned short* __restrict__ Binv,
        const unsigned short* __restrict__ fc1t, const float* __restrict__ b1,
        const float* __restrict__ fc2, const float* __restrict__ b2, float* __restrict__ out) {
    int t = threadIdx.x, wv = t >> 6, l = t & 63, lo = l & 15, hi = l >> 4;
    int b = blockIdx.y;
    int nb = (blockIdx.x * 4 + wv) * 16;
    const unsigned short* Arow = Binv + ((long)b * NP + nb + lo) * KTOT + 128 + hi * 8;
    f32x4 acc[8];
    #pragma unroll
    for (int ft = 0; ft < 8; ++ft) acc[ft] = (f32x4){0.f, 0.f, 0.f, 0.f};
    #pragma unroll
    for (int ks = 0; ks < 4; ++ks) {
        bf16x8 a = *(const bf16x8*)(Arow + ks * 32);
        #pragma unroll
        for (int ft = 0; ft < 8; ++ft) {
            bf16x8 bv = *(const bf16x8*)(fc1t + (ft * 16 + lo) * 128 + ks * 32 + hi * 8);
            acc[ft] = __builtin_amdgcn_mfma_f32_16x16x32_bf16(a, bv, acc[ft], 0, 0, 0);
        }
    }
    float s[4] = {0.f, 0.f, 0.f, 0.f};
    #pragma unroll
    for (int ft = 0; ft < 8; ++ft) {
        int f = ft * 16 + lo;
        float b1f = b1[f], f2f = fc2[f];
        #pragma unroll
        for (int r = 0; r < 4; ++r) s[r] += gelu_exact(acc[ft][r] + b1f) * f2f;
    }
    float b2v = b2[0];
    #pragma unroll
    for (int r = 0; r < 4; ++r) {
        float v = s[r];
        v += __shfl_xor(v, 1); v += __shfl_xor(v, 2);
        v += __shfl_xor(v, 4); v += __shfl_xor(v, 8);
        if (lo == 0) out[(long)b * NN + nb + hi * 4 + r] = v + b2v;
    }
}

extern "C" void kernel_launch(void* const* d_in, const int* in_sizes, int n_in,
                              void* d_out, int out_size, void* d_ws, size_t ws_size,
                              hipStream_t stream) {
    const float* x     = (const float*)d_in[0];
    const float* mask  = (const float*)d_in[1];
    const float* nodes = (const float*)d_in[2];
    const float* wts   = (const float*)d_in[3];
    // d_in[4] directed_edges, d_in[5] edge_gradient_weights: dead (x3 never added)
    const float* modes = (const float*)d_in[6];
    const float* fc0w  = (const float*)d_in[7];
    const float* fc0b  = (const float*)d_in[8];
    const float* spwc  = (const float*)d_in[9];
    const float* spws  = (const float*)d_in[10];
    const float* spw0  = (const float*)d_in[11];
    const float* ww    = (const float*)d_in[12];
    const float* wb    = (const float*)d_in[13];
    // d_in[14] gw_w, d_in[15] gw_b: dead
    const float* fc1w  = (const float*)d_in[16];
    const float* fc1b  = (const float*)d_in[17];
    const float* fc2w  = (const float*)d_in[18];
    const float* fc2b  = (const float*)d_in[19];

    char* p = (char*)d_ws;
    auto alloc = [&](size_t bytes) { char* r = p; p += (bytes + 255) & ~255UL; return r; };
    unsigned short* Binv = (unsigned short*)alloc((size_t)BATCH * NP * KTOT * 2);
    unsigned short* wbcs = (unsigned short*)alloc((size_t)BATCH * MODES * NP * 2);
    unsigned short* hcn  = (unsigned short*)alloc((size_t)BATCH * CC * NP * 2);
    unsigned short* Amat = (unsigned short*)alloc((size_t)BATCH * CC * KTOT * 2);
    unsigned short* fc1t = (unsigned short*)alloc((size_t)CC * 128 * 2);
    float* pxcs = (float*)alloc((size_t)FSPLITS * BATCH * CC * MODES * 4);
    float* xcb  = (float*)alloc((size_t)BATCH * CC * KK * 4);
    float* xsb  = (float*)alloc((size_t)BATCH * CC * KK * 4);
    float* x0b  = (float*)alloc((size_t)BATCH * CC * 4);
    float* f0a  = (float*)alloc((size_t)BATCH * CC * 4);
    float* wba  = (float*)alloc((size_t)BATCH * CC * 4);
    float* maskp = (float*)alloc((size_t)BATCH * NP * 4);

    basis_kernel<<<(BATCH * NP) / 256, 256, 0, stream>>>(nodes, mask, wts, modes, wbcs, Binv, maskp);
    lift_binv<<<(BATCH * NP) / 2, 256, 0, stream>>>(x, fc0w, fc0b, Binv);
    lift_hcn<<<(BATCH * CC * NP / 8) / 256, 256, 0, stream>>>(x, fc0w, fc0b, hcn);
    fc1t_kernel<<<64, 256, 0, stream>>>(fc1w, fc1t);

    for (int l = 0; l < NLAYER; ++l) {
        forward_mfma<<<dim3(FSPLITS, 2, BATCH), 256, 0, stream>>>(hcn, wbcs, pxcs);
        reduce_kernel<<<(BATCH * CC * MODES) / 256, 256, 0, stream>>>(pxcs, xcb, xsb, x0b);
        mix_kernel<<<dim3(CC, BATCH), 256, 0, stream>>>(xcb, xsb, x0b, spwc, spws, spw0,
                                                        ww, wb, Amat, f0a, wba, l);
        if (l < NLAYER - 1)
            inverse_mfma<1, 1><<<dim3(NP / 64, BATCH), 256, 0, stream>>>(
                Amat, Binv, f0a, wba, maskp, hcn);
        else
            inverse_mfma<0, 0><<<dim3(NP / 64, BATCH), 256, 0, stream>>>(
                Amat, Binv, f0a, wba, maskp, hcn);
    }
    head_mfma<<<dim3(NN / 64, BATCH), 256, 0, stream>>>(Binv, fc1t, fc1b, fc2w, fc2b, (float*)d_out);
}

// Round 4
// 246.273 us; speedup vs baseline: 3.9511x; 1.4224x over previous
//
#include <hip/hip_runtime.h>
#include <math.h>

#define NN 40000
#define NP 40064          // 313 * 128, padded node count
#define CC 128
#define KK 64
#define BATCH 2
#define NLAYER 4
#define FSPLITS 128
#define MODES 144         // 64 cos + 64 sin + 1 zero-mode + 15 zero pad
#define KTOT 256          // inverse GEMM contraction: 64 bc + 64 bs + 128 h
#define NCH 626           // NP / 64

typedef __attribute__((ext_vector_type(8))) short bf16x8;
typedef __attribute__((ext_vector_type(4))) float f32x4;
typedef __attribute__((ext_vector_type(4))) unsigned short u16x4;
typedef __attribute__((ext_vector_type(8))) unsigned short u16x8;

__device__ __forceinline__ float gelu_exact(float x) {
    return 0.5f * x * (1.0f + erff(x * 0.70710678118654752f));
}
__device__ __forceinline__ unsigned short f2bf(float x) {   // RNE float->bf16
    unsigned int u = __float_as_uint(x);
    u += 0x7FFFu + ((u >> 16) & 1u);
    return (unsigned short)(u >> 16);
}

// ---------- basis: fills wbcs [B][144][NP] (bf16), Binv cols 0..127 (bf16), maskp ----------
__global__ __launch_bounds__(256) void basis_kernel(
        const float* __restrict__ nodes, const float* __restrict__ mask,
        const float* __restrict__ wts, const float* __restrict__ modes,
        unsigned short* __restrict__ wbcs, unsigned short* __restrict__ Binv,
        float* __restrict__ maskp) {
    __shared__ float sm[KK * 2];
    int t = threadIdx.x;
    if (t < KK * 2) sm[t] = modes[t];
    __syncthreads();
    int idx = blockIdx.x * 256 + t;          // over B*NP (exact)
    int b = idx / NP, n = idx - b * NP;
    float nx = 0.f, ny = 0.f, m = 0.f, w = 0.f;
    if (n < NN) {
        long gi = (long)b * NN + n;
        nx = nodes[gi * 2]; ny = nodes[gi * 2 + 1];
        m = mask[gi]; w = wts[gi];
    }
    float mw = m * w;
    unsigned short* wrow = wbcs + (long)b * MODES * NP + n;
    unsigned int bcp[32], bsp[32];
    #pragma unroll
    for (int k2 = 0; k2 < 32; ++k2) {
        float t0 = nx * sm[4 * k2]     + ny * sm[4 * k2 + 1];
        float t1 = nx * sm[4 * k2 + 2] + ny * sm[4 * k2 + 3];
        float s0, c0, s1, c1;
        __sincosf(t0, &s0, &c0);
        __sincosf(t1, &s1, &c1);
        int k0 = 2 * k2;
        wrow[(long)k0 * NP]            = f2bf(c0 * mw);
        wrow[(long)(k0 + 1) * NP]      = f2bf(c1 * mw);
        wrow[(long)(64 + k0) * NP]     = f2bf(s0 * mw);
        wrow[(long)(64 + k0 + 1) * NP] = f2bf(s1 * mw);
        bcp[k2] = (unsigned int)f2bf(c0 * m) | ((unsigned int)f2bf(c1 * m) << 16);
        bsp[k2] = (unsigned int)f2bf(s0 * m) | ((unsigned int)f2bf(s1 * m) << 16);
    }
    wrow[(long)128 * NP] = f2bf(mw);
    #pragma unroll
    for (int r = 129; r < MODES; ++r) wrow[(long)r * NP] = 0;
    maskp[idx] = m;
    uint4* brow = (uint4*)(Binv + (long)idx * KTOT);
    #pragma unroll
    for (int q = 0; q < 8; ++q)
        brow[q] = make_uint4(bcp[4*q], bcp[4*q+1], bcp[4*q+2], bcp[4*q+3]);
    #pragma unroll
    for (int q = 0; q < 8; ++q)
        brow[8 + q] = make_uint4(bsp[4*q], bsp[4*q+1], bsp[4*q+2], bsp[4*q+3]);
}

// ---------- fc1 transpose to [f][c] bf16 ----------
__global__ void fc1t_kernel(const float* __restrict__ fc1, unsigned short* __restrict__ fc1t) {
    int idx = blockIdx.x * 256 + threadIdx.x;    // 16384
    int f = idx >> 7, c = idx & 127;
    fc1t[f * 128 + c] = f2bf(fc1[c * 128 + f]);
}

// ---------- lift + layer-0 forward partials (fused) ----------
// grid (FSPLITS, BATCH), 512 thr = 8 waves. Writes Binv h-region + pxcs partials.
__global__ __launch_bounds__(512) void lift_fused(const float* __restrict__ x,
        const float* __restrict__ w, const float* __restrict__ bvec,
        const unsigned short* __restrict__ wbcs,
        unsigned short* __restrict__ Binv, float* __restrict__ pxcs) {
    int s = blockIdx.x, b = blockIdx.y;
    int t = threadIdx.x, wv = t >> 6, l = t & 63, lo = l & 15, hi = l >> 4;
    __shared__ __align__(16) char lds[52224];
    char* Ts  = lds;              // [64 n][128 o]u16, swizzled
    char* Ts2 = lds + 16384;      // [128 c][64 n]u16, swizzled
    char* Wt  = lds + 32768;      // wbcs tile 18432
    float* xl = (float*)(lds + 51200);   // x chunk [64][3]
    int c = t & 127, ng = t >> 7;
    float w0 = w[c], w1 = w[CC + c], w2 = w[2 * CC + c], bv = bvec[c];
    f32x4 accF[9];
    #pragma unroll
    for (int mt = 0; mt < 9; ++mt) accF[mt] = (f32x4){0.f, 0.f, 0.f, 0.f};
    const char* Wsrc = (const char*)wbcs + (long)b * MODES * NP * 2;

    for (int chunk = s; chunk < NCH; chunk += FSPLITS) {
        int nbase = chunk * 64;
        __syncthreads();
        if (nbase < NN && t < 192) xl[t] = x[((long)b * NN + nbase) * 3 + t];
        #pragma unroll
        for (int j = 0; j < 3; ++j) {
            int off = j * 8192 + t * 16;
            if (off < 18432) {
                int row = off >> 7, col = off & 127;
                uint4 v = *(const uint4*)(Wsrc + (long)row * (NP * 2) + nbase * 2 + col);
                *(uint4*)(Wt + (off ^ ((row & 7) << 4))) = v;
            }
        }
        __syncthreads();
        u16x8 hv0, hv1;
        #pragma unroll
        for (int j = 0; j < 16; ++j) {
            int n = ng * 16 + j;
            float h = 0.f;
            if (nbase < NN) h = bv + xl[n * 3] * w0 + xl[n * 3 + 1] * w1 + xl[n * 3 + 2] * w2;
            unsigned short hb = f2bf(h);
            if (j < 8) hv0[j] = hb; else hv1[j - 8] = hb;
            *(unsigned short*)(Ts + (((n << 8) + c * 2) ^ ((n & 7) << 4))) = hb;
        }
        int base2 = c * 128 + ng * 32;
        *(u16x8*)(Ts2 + (base2 ^ ((c & 7) << 4))) = hv0;
        *(u16x8*)(Ts2 + ((base2 + 16) ^ ((c & 7) << 4))) = hv1;
        __syncthreads();
        char* Bdst = (char*)Binv + ((long)b * NP + nbase) * 512 + 256;
        #pragma unroll
        for (int pass = 0; pass < 2; ++pass) {
            int n = pass * 32 + (t >> 4), seg = t & 15;
            uint4 v = *(const uint4*)(Ts + (((n << 8) + (seg << 4)) ^ ((n & 7) << 4)));
            *(uint4*)(Bdst + (long)n * 512 + seg * 16) = v;
        }
        int ct = wv * 16;
        #pragma unroll
        for (int ks2 = 0; ks2 < 2; ++ks2) {
            int ar = ct + lo;
            bf16x8 a = *(const bf16x8*)(Ts2 + ((ar * 128 + ks2 * 64 + hi * 16) ^ ((ar & 7) << 4)));
            #pragma unroll
            for (int mt = 0; mt < 9; ++mt) {
                int mrow = mt * 16 + lo;
                bf16x8 bb = *(const bf16x8*)(Wt + ((mrow * 128 + ks2 * 64 + hi * 16) ^ ((mrow & 7) << 4)));
                accF[mt] = __builtin_amdgcn_mfma_f32_16x16x32_bf16(a, bb, accF[mt], 0, 0, 0);
            }
        }
    }
    float* pb = pxcs + ((long)s * BATCH + b) * CC * MODES;
    #pragma unroll
    for (int mt = 0; mt < 9; ++mt)
        #pragma unroll
        for (int r = 0; r < 4; ++r)
            pb[(long)(wv * 16 + hi * 4 + r) * MODES + mt * 16 + lo] = accF[mt][r];
}

// ---------- reduce split partials -> xc, xs, x0 (8 lanes per output) ----------
__global__ __launch_bounds__(256) void reduce_kernel(const float* __restrict__ pxcs,
        float* __restrict__ xc, float* __restrict__ xs, float* __restrict__ x0) {
    int gid = blockIdx.x * 256 + threadIdx.x;    // 8 * 36864 = 294912 total
    int idx = gid >> 3, sg = gid & 7;
    float a = 0.f;
    #pragma unroll
    for (int j = 0; j < 16; ++j)
        a += pxcs[(long)(sg * 16 + j) * (BATCH * CC * MODES) + idx];
    a += __shfl_xor(a, 1); a += __shfl_xor(a, 2); a += __shfl_xor(a, 4);
    if (sg == 0) {
        int m = idx % MODES, bc_ = idx / MODES;
        if (m < 64)        xc[bc_ * KK + m] = a;
        else if (m < 128)  xs[bc_ * KK + m - 64] = a;
        else if (m == 128) x0[bc_] = a;
    }
}

// ---------- mix: assemble A=[2fc|-2fs|ww] bf16, f0/wb fp32 ----------
__global__ __launch_bounds__(256) void mix_kernel(const float* __restrict__ xc,
        const float* __restrict__ xs, const float* __restrict__ x0,
        const float* __restrict__ wc, const float* __restrict__ wsp,
        const float* __restrict__ w0, const float* __restrict__ ww,
        const float* __restrict__ wbias, unsigned short* __restrict__ A,
        float* __restrict__ f0a, float* __restrict__ wba, int layer) {
    int o = blockIdx.x, b = blockIdx.y;
    int k = threadIdx.x & 63, ig = threadIdx.x >> 6;
    const float* wcl = wc  + (long)layer * CC * CC * KK;
    const float* wsl = wsp + (long)layer * CC * CC * KK;
    float fc = 0.f, fs = 0.f;
    for (int i = ig * 32; i < ig * 32 + 32; ++i) {
        float xci = xc[(b * CC + i) * KK + k];
        float xsi = xs[(b * CC + i) * KK + k];
        float wcv = wcl[((long)i * CC + o) * KK + k];
        float wsv = wsl[((long)i * CC + o) * KK + k];
        fc += xci * wcv + xsi * wsv;
        fs += xci * wsv - xsi * wcv;
    }
    __shared__ float rc[4][64], rs[4][64];
    rc[ig][k] = fc; rs[ig][k] = fs;
    __syncthreads();
    unsigned short* Ar = A + ((long)b * CC + o) * KTOT;
    if (ig == 0) {
        fc = rc[0][k] + rc[1][k] + rc[2][k] + rc[3][k];
        fs = rs[0][k] + rs[1][k] + rs[2][k] + rs[3][k];
        Ar[k]      = f2bf(2.f * fc);
        Ar[64 + k] = f2bf(-2.f * fs);
    } else if (ig == 1) {
        const float* wwl = ww + ((long)layer * CC + o) * CC;
        Ar[128 + k] = f2bf(wwl[k]);
        Ar[192 + k] = f2bf(wwl[64 + k]);
    } else if (ig == 2) {
        const float* w0l = w0 + (long)layer * CC * CC;
        float p = x0[b * CC + k] * w0l[(long)k * CC + o]
                + x0[b * CC + 64 + k] * w0l[(long)(64 + k) * CC + o];
        #pragma unroll
        for (int off = 32; off > 0; off >>= 1) p += __shfl_down(p, off, 64);
        if (k == 0) { f0a[b * CC + o] = p; wba[b * CC + o] = wbias[layer * CC + o]; }
    }
}

// ---------- fused inverse + next-layer forward partials ----------
// grid (FSPLITS, BATCH), 512 thr = 8 waves; wave tile 16o x 64n; grid-stride over n-chunks.
template <int DO_FWD, int DOGELU>
__global__ __launch_bounds__(512) void fused_inv(const unsigned short* __restrict__ Amat,
        unsigned short* Binv, const unsigned short* __restrict__ wbcs,
        const float* __restrict__ f0a, const float* __restrict__ wba,
        const float* __restrict__ maskp, float* __restrict__ pxcs) {
    int s = blockIdx.x, b = blockIdx.y;
    int t = threadIdx.x, wv = t >> 6, l = t & 63, lo = l & 15, hi = l >> 4;
    __shared__ __align__(16) char lds[51200];
    char* Btile = lds;            // 32 KB staging; overlaid after use by:
    char* Ts    = lds;            //   [64 n][128 o]u16 (16 KB)
    char* Ts2   = lds + 16384;    //   [128 c][64 n]u16 (16 KB)
    char* Wt    = lds + 32768;    // wbcs tile 18432 B
    const unsigned short* Ab = Amat + (long)b * CC * KTOT;
    bf16x8 af[8];
    {
        const unsigned short* arow = Ab + (long)(wv * 16 + lo) * KTOT + hi * 8;
        #pragma unroll
        for (int ks = 0; ks < 8; ++ks) af[ks] = *(const bf16x8*)(arow + ks * 32);
    }
    int o0 = wv * 16 + hi * 4;
    f32x4 f0v = *(const f32x4*)(f0a + b * CC + o0);
    f32x4 wbv = *(const f32x4*)(wba + b * CC + o0);
    int swz = (lo & 7) << 4;
    f32x4 accF[9];
    #pragma unroll
    for (int mt = 0; mt < 9; ++mt) accF[mt] = (f32x4){0.f, 0.f, 0.f, 0.f};
    const char* Wsrc = (const char*)wbcs + (long)b * MODES * NP * 2;

    for (int chunk = s; chunk < NCH; chunk += FSPLITS) {
        int nbase = chunk * 64;
        __syncthreads();   // previous iter's Ts/Ts2/Wt reads complete
        const char* Bsrc = (const char*)Binv + ((long)b * NP + nbase) * 512;
        #pragma unroll
        for (int i = 0; i < 4; ++i) {
            int off = i * 8192 + t * 16;
            int row = off >> 9;
            uint4 v = *(const uint4*)(Bsrc + off);
            *(uint4*)(Btile + (off ^ ((row & 7) << 4))) = v;
        }
        if (DO_FWD) {
            #pragma unroll
            for (int j = 0; j < 3; ++j) {
                int off = j * 8192 + t * 16;
                if (off < 18432) {
                    int row = off >> 7, col = off & 127;
                    uint4 v = *(const uint4*)(Wsrc + (long)row * (NP * 2) + nbase * 2 + col);
                    *(uint4*)(Wt + (off ^ ((row & 7) << 4))) = v;
                }
            }
        }
        __syncthreads();
        f32x4 acc[4];
        #pragma unroll
        for (int fn = 0; fn < 4; ++fn) acc[fn] = (f32x4){0.f, 0.f, 0.f, 0.f};
        #pragma unroll
        for (int ks = 0; ks < 8; ++ks) {
            #pragma unroll
            for (int fn = 0; fn < 4; ++fn) {
                int boff = ((fn * 16 + lo) << 9) + (ks << 6) + (hi << 4);
                bf16x8 bb = *(const bf16x8*)(Btile + (boff ^ swz));
                acc[fn] = __builtin_amdgcn_mfma_f32_16x16x32_bf16(af[ks], bb, acc[fn], 0, 0, 0);
            }
        }
        __syncthreads();   // Btile reads done; overlay with Ts/Ts2
        #pragma unroll
        for (int fn = 0; fn < 4; ++fn) {
            int n = fn * 16 + lo;
            float mv = maskp[(long)b * NP + nbase + n];
            u16x4 pk;
            #pragma unroll
            for (int r = 0; r < 4; ++r) {
                float v = acc[fn][r] + f0v[r] * mv + wbv[r];
                if (DOGELU) v = gelu_exact(v);
                pk[r] = f2bf(v);
                if (DO_FWD)
                    *(unsigned short*)(Ts2 + (((o0 + r) * 128 + n * 2) ^ (((o0 + r) & 7) << 4))) = pk[r];
            }
            *(u16x4*)(Ts + (((n << 8) + (o0 << 1)) ^ ((n & 7) << 4))) = pk;
        }
        __syncthreads();
        char* Bdst = (char*)Binv + ((long)b * NP + nbase) * 512 + 256;
        #pragma unroll
        for (int pass = 0; pass < 2; ++pass) {
            int n = pass * 32 + (t >> 4), seg = t & 15;
            uint4 v = *(const uint4*)(Ts + (((n << 8) + (seg << 4)) ^ ((n & 7) << 4)));
            *(uint4*)(Bdst + (long)n * 512 + seg * 16) = v;
        }
        if (DO_FWD) {
            int ct = wv * 16;
            #pragma unroll
            for (int ks2 = 0; ks2 < 2; ++ks2) {
                int ar = ct + lo;
                bf16x8 a = *(const bf16x8*)(Ts2 + ((ar * 128 + ks2 * 64 + hi * 16) ^ ((ar & 7) << 4)));
                #pragma unroll
                for (int mt = 0; mt < 9; ++mt) {
                    int mrow = mt * 16 + lo;
                    bf16x8 bb = *(const bf16x8*)(Wt + ((mrow * 128 + ks2 * 64 + hi * 16) ^ ((mrow & 7) << 4)));
                    accF[mt] = __builtin_amdgcn_mfma_f32_16x16x32_bf16(a, bb, accF[mt], 0, 0, 0);
                }
            }
        }
    }
    if (DO_FWD) {
        float* pb = pxcs + ((long)s * BATCH + b) * CC * MODES;
        #pragma unroll
        for (int mt = 0; mt < 9; ++mt)
            #pragma unroll
            for (int r = 0; r < 4; ++r)
                pb[(long)(wv * 16 + hi * 4 + r) * MODES + mt * 16 + lo] = accF[mt][r];
    }
}

// ---------- head: out = gelu(hT@fc1 + b1) @ fc2 + b2 ----------
__global__ __launch_bounds__(256) void head_mfma(const unsigned short* __restrict__ Binv,
        const unsigned short* __restrict__ fc1t, const float* __restrict__ b1,
        const float* __restrict__ fc2, const float* __restrict__ b2, float* __restrict__ out) {
    int t = threadIdx.x, wv = t >> 6, l = t & 63, lo = l & 15, hi = l >> 4;
    int b = blockIdx.y;
    int nb = (blockIdx.x * 4 + wv) * 16;
    const unsigned short* Arow = Binv + ((long)b * NP + nb + lo) * KTOT + 128 + hi * 8;
    f32x4 acc[8];
    #pragma unroll
    for (int ft = 0; ft < 8; ++ft) acc[ft] = (f32x4){0.f, 0.f, 0.f, 0.f};
    #pragma unroll
    for (int ks = 0; ks < 4; ++ks) {
        bf16x8 a = *(const bf16x8*)(Arow + ks * 32);
        #pragma unroll
        for (int ft = 0; ft < 8; ++ft) {
            bf16x8 bv = *(const bf16x8*)(fc1t + (ft * 16 + lo) * 128 + ks * 32 + hi * 8);
            acc[ft] = __builtin_amdgcn_mfma_f32_16x16x32_bf16(a, bv, acc[ft], 0, 0, 0);
        }
    }
    float s[4] = {0.f, 0.f, 0.f, 0.f};
    #pragma unroll
    for (int ft = 0; ft < 8; ++ft) {
        int f = ft * 16 + lo;
        float b1f = b1[f], f2f = fc2[f];
        #pragma unroll
        for (int r = 0; r < 4; ++r) s[r] += gelu_exact(acc[ft][r] + b1f) * f2f;
    }
    float b2v = b2[0];
    #pragma unroll
    for (int r = 0; r < 4; ++r) {
        float v = s[r];
        v += __shfl_xor(v, 1); v += __shfl_xor(v, 2);
        v += __shfl_xor(v, 4); v += __shfl_xor(v, 8);
        if (lo == 0) out[(long)b * NN + nb + hi * 4 + r] = v + b2v;
    }
}

extern "C" void kernel_launch(void* const* d_in, const int* in_sizes, int n_in,
                              void* d_out, int out_size, void* d_ws, size_t ws_size,
                              hipStream_t stream) {
    const float* x     = (const float*)d_in[0];
    const float* mask  = (const float*)d_in[1];
    const float* nodes = (const float*)d_in[2];
    const float* wts   = (const float*)d_in[3];
    // d_in[4] directed_edges, d_in[5] edge_gradient_weights: dead (x3 never added)
    const float* modes = (const float*)d_in[6];
    const float* fc0w  = (const float*)d_in[7];
    const float* fc0b  = (const float*)d_in[8];
    const float* spwc  = (const float*)d_in[9];
    const float* spws  = (const float*)d_in[10];
    const float* spw0  = (const float*)d_in[11];
    const float* ww    = (const float*)d_in[12];
    const float* wb    = (const float*)d_in[13];
    // d_in[14] gw_w, d_in[15] gw_b: dead
    const float* fc1w  = (const float*)d_in[16];
    const float* fc1b  = (const float*)d_in[17];
    const float* fc2w  = (const float*)d_in[18];
    const float* fc2b  = (const float*)d_in[19];

    char* p = (char*)d_ws;
    auto alloc = [&](size_t bytes) { char* r = p; p += (bytes + 255) & ~255UL; return r; };
    unsigned short* Binv = (unsigned short*)alloc((size_t)BATCH * NP * KTOT * 2);
    unsigned short* wbcs = (unsigned short*)alloc((size_t)BATCH * MODES * NP * 2);
    unsigned short* Amat = (unsigned short*)alloc((size_t)BATCH * CC * KTOT * 2);
    unsigned short* fc1t = (unsigned short*)alloc((size_t)CC * 128 * 2);
    float* pxcs = (float*)alloc((size_t)FSPLITS * BATCH * CC * MODES * 4);
    float* xcb  = (float*)alloc((size_t)BATCH * CC * KK * 4);
    float* xsb  = (float*)alloc((size_t)BATCH * CC * KK * 4);
    float* x0b  = (float*)alloc((size_t)BATCH * CC * 4);
    float* f0a  = (float*)alloc((size_t)BATCH * CC * 4);
    float* wba  = (float*)alloc((size_t)BATCH * CC * 4);
    float* maskp = (float*)alloc((size_t)BATCH * NP * 4);

    basis_kernel<<<(BATCH * NP) / 256, 256, 0, stream>>>(nodes, mask, wts, modes, wbcs, Binv, maskp);
    fc1t_kernel<<<64, 256, 0, stream>>>(fc1w, fc1t);
    lift_fused<<<dim3(FSPLITS, BATCH), 512, 0, stream>>>(x, fc0w, fc0b, wbcs, Binv, pxcs);

    for (int l = 0; l < NLAYER; ++l) {
        reduce_kernel<<<(8 * BATCH * CC * MODES) / 256, 256, 0, stream>>>(pxcs, xcb, xsb, x0b);
        mix_kernel<<<dim3(CC, BATCH), 256, 0, stream>>>(xcb, xsb, x0b, spwc, spws, spw0,
                                                        ww, wb, Amat, f0a, wba, l);
        if (l < NLAYER - 1)
            fused_inv<1, 1><<<dim3(FSPLITS, BATCH), 512, 0, stream>>>(
                Amat, Binv, wbcs, f0a, wba, maskp, pxcs);
        else
            fused_inv<0, 0><<<dim3(FSPLITS, BATCH), 512, 0, stream>>>(
                Amat, Binv, wbcs, f0a, wba, maskp, pxcs);
    }
    head_mfma<<<dim3(NN / 64, BATCH), 256, 0, stream>>>(Binv, fc1t, fc1b, fc2w, fc2b, (float*)d_out);
}

// Round 5
// 223.720 us; speedup vs baseline: 4.3494x; 1.1008x over previous
//
#include <hip/hip_runtime.h>
#include <math.h>

#define NN 40000
#define NP 40064          // 313 * 128, padded node count
#define CC 128
#define KK 64
#define BATCH 2
#define NLAYER 4
#define FSPLITS 128
#define MODES 144         // 64 cos + 64 sin + 1 zero-mode + 15 zero pad
#define KTOT 256          // inverse GEMM contraction: 64 bc + 64 bs + 128 h
#define NCH 626           // NP / 64

typedef __attribute__((ext_vector_type(8))) short bf16x8;
typedef __attribute__((ext_vector_type(4))) float f32x4;
typedef __attribute__((ext_vector_type(4))) unsigned short u16x4;
typedef __attribute__((ext_vector_type(8))) unsigned short u16x8;

__device__ __forceinline__ float gelu_exact(float x) {
    return 0.5f * x * (1.0f + erff(x * 0.70710678118654752f));
}
__device__ __forceinline__ unsigned short f2bf(float x) {   // RNE float->bf16
    unsigned int u = __float_as_uint(x);
    u += 0x7FFFu + ((u >> 16) & 1u);
    return (unsigned short)(u >> 16);
}

// ---------- basis: fills wbcs [B][144][NP] (bf16), Binv cols 0..127 (bf16), maskp ----------
__global__ __launch_bounds__(256) void basis_kernel(
        const float* __restrict__ nodes, const float* __restrict__ mask,
        const float* __restrict__ wts, const float* __restrict__ modes,
        unsigned short* __restrict__ wbcs, unsigned short* __restrict__ Binv,
        float* __restrict__ maskp) {
    __shared__ float sm[KK * 2];
    int t = threadIdx.x;
    if (t < KK * 2) sm[t] = modes[t];
    __syncthreads();
    int idx = blockIdx.x * 256 + t;          // over B*NP (exact)
    int b = idx / NP, n = idx - b * NP;
    float nx = 0.f, ny = 0.f, m = 0.f, w = 0.f;
    if (n < NN) {
        long gi = (long)b * NN + n;
        nx = nodes[gi * 2]; ny = nodes[gi * 2 + 1];
        m = mask[gi]; w = wts[gi];
    }
    float mw = m * w;
    unsigned short* wrow = wbcs + (long)b * MODES * NP + n;
    unsigned int bcp[32], bsp[32];
    #pragma unroll
    for (int k2 = 0; k2 < 32; ++k2) {
        float t0 = nx * sm[4 * k2]     + ny * sm[4 * k2 + 1];
        float t1 = nx * sm[4 * k2 + 2] + ny * sm[4 * k2 + 3];
        float s0, c0, s1, c1;
        __sincosf(t0, &s0, &c0);
        __sincosf(t1, &s1, &c1);
        int k0 = 2 * k2;
        wrow[(long)k0 * NP]            = f2bf(c0 * mw);
        wrow[(long)(k0 + 1) * NP]      = f2bf(c1 * mw);
        wrow[(long)(64 + k0) * NP]     = f2bf(s0 * mw);
        wrow[(long)(64 + k0 + 1) * NP] = f2bf(s1 * mw);
        bcp[k2] = (unsigned int)f2bf(c0 * m) | ((unsigned int)f2bf(c1 * m) << 16);
        bsp[k2] = (unsigned int)f2bf(s0 * m) | ((unsigned int)f2bf(s1 * m) << 16);
    }
    wrow[(long)128 * NP] = f2bf(mw);
    #pragma unroll
    for (int r = 129; r < MODES; ++r) wrow[(long)r * NP] = 0;
    maskp[idx] = m;
    uint4* brow = (uint4*)(Binv + (long)idx * KTOT);
    #pragma unroll
    for (int q = 0; q < 8; ++q)
        brow[q] = make_uint4(bcp[4*q], bcp[4*q+1], bcp[4*q+2], bcp[4*q+3]);
    #pragma unroll
    for (int q = 0; q < 8; ++q)
        brow[8 + q] = make_uint4(bsp[4*q], bsp[4*q+1], bsp[4*q+2], bsp[4*q+3]);
}

// ---------- fc1 transpose to [f][c] bf16 ----------
__global__ void fc1t_kernel(const float* __restrict__ fc1, unsigned short* __restrict__ fc1t) {
    int idx = blockIdx.x * 256 + threadIdx.x;    // 16384
    int f = idx >> 7, c = idx & 127;
    fc1t[f * 128 + c] = f2bf(fc1[c * 128 + f]);
}

// ---------- lift + layer-0 forward partials (fused, T14 prefetch) ----------
__global__ __launch_bounds__(512) void lift_fused(const float* __restrict__ x,
        const float* __restrict__ w, const float* __restrict__ bvec,
        const unsigned short* __restrict__ wbcs,
        unsigned short* __restrict__ Binv, float* __restrict__ pxcs) {
    int s = blockIdx.x, b = blockIdx.y;
    int t = threadIdx.x, wv = t >> 6, l = t & 63, lo = l & 15, hi = l >> 4;
    __shared__ __align__(16) char lds[52224];
    char* Ts  = lds;              // [64 n][128 o]u16, swizzled
    char* Ts2 = lds + 16384;      // [128 c][64 n]u16, swizzled
    char* Wt  = lds + 32768;      // wbcs tile 18432
    float* xl = (float*)(lds + 51200);   // x chunk [64][3]
    int c = t & 127, ng = t >> 7;
    float w0 = w[c], w1 = w[CC + c], w2 = w[2 * CC + c], bv = bvec[c];
    f32x4 accF[9];
    #pragma unroll
    for (int mt = 0; mt < 9; ++mt) accF[mt] = (f32x4){0.f, 0.f, 0.f, 0.f};
    const char* Wsrc = (const char*)wbcs + (long)b * MODES * NP * 2;

    int off0 = t * 16, off1 = 8192 + t * 16, off2 = 16384 + t * 16;
    uint4 pW0 = {}, pW1 = {}, pW2 = {};
    float pxv = 0.f;
    {   // prefetch first chunk
        long n0b = (long)s * 128;
        pW0 = *(const uint4*)(Wsrc + (long)(off0 >> 7) * (NP * 2) + n0b + (off0 & 127));
        pW1 = *(const uint4*)(Wsrc + (long)(off1 >> 7) * (NP * 2) + n0b + (off1 & 127));
        if (t < 128)
            pW2 = *(const uint4*)(Wsrc + (long)(off2 >> 7) * (NP * 2) + n0b + (off2 & 127));
        if (t < 192) pxv = x[((long)b * NN + s * 64) * 3 + t];
    }

    for (int chunk = s; chunk < NCH; chunk += FSPLITS) {
        __syncthreads();   // prev iter's Ts/Ts2/Wt reads complete
        // commit prefetched regs to LDS
        *(uint4*)(Wt + (off0 ^ (((off0 >> 7) & 7) << 4))) = pW0;
        *(uint4*)(Wt + (off1 ^ (((off1 >> 7) & 7) << 4))) = pW1;
        if (t < 128) *(uint4*)(Wt + (off2 ^ (((off2 >> 7) & 7) << 4))) = pW2;
        if (t < 192) xl[t] = pxv;
        // issue next chunk's loads (fly during compute)
        int nc = chunk + FSPLITS;
        if (nc < NCH) {
            long n0b = (long)nc * 128;
            pW0 = *(const uint4*)(Wsrc + (long)(off0 >> 7) * (NP * 2) + n0b + (off0 & 127));
            pW1 = *(const uint4*)(Wsrc + (long)(off1 >> 7) * (NP * 2) + n0b + (off1 & 127));
            if (t < 128)
                pW2 = *(const uint4*)(Wsrc + (long)(off2 >> 7) * (NP * 2) + n0b + (off2 & 127));
            if (nc * 64 < NN && t < 192) pxv = x[((long)b * NN + nc * 64) * 3 + t];
        }
        __syncthreads();
        int nbase = chunk * 64;
        u16x8 hv0, hv1;
        #pragma unroll
        for (int j = 0; j < 16; ++j) {
            int n = ng * 16 + j;
            float h = 0.f;
            if (nbase < NN) h = bv + xl[n * 3] * w0 + xl[n * 3 + 1] * w1 + xl[n * 3 + 2] * w2;
            unsigned short hb = f2bf(h);
            if (j < 8) hv0[j] = hb; else hv1[j - 8] = hb;
            *(unsigned short*)(Ts + (((n << 8) + c * 2) ^ ((n & 7) << 4))) = hb;
        }
        int base2 = c * 128 + ng * 32;
        *(u16x8*)(Ts2 + (base2 ^ ((c & 7) << 4))) = hv0;
        *(u16x8*)(Ts2 + ((base2 + 16) ^ ((c & 7) << 4))) = hv1;
        __syncthreads();
        char* Bdst = (char*)Binv + ((long)b * NP + nbase) * 512 + 256;
        #pragma unroll
        for (int pass = 0; pass < 2; ++pass) {
            int n = pass * 32 + (t >> 4), seg = t & 15;
            uint4 v = *(const uint4*)(Ts + (((n << 8) + (seg << 4)) ^ ((n & 7) << 4)));
            *(uint4*)(Bdst + (long)n * 512 + seg * 16) = v;
        }
        int ct = wv * 16;
        #pragma unroll
        for (int ks2 = 0; ks2 < 2; ++ks2) {
            int ar = ct + lo;
            bf16x8 a = *(const bf16x8*)(Ts2 + ((ar * 128 + ks2 * 64 + hi * 16) ^ ((ar & 7) << 4)));
            #pragma unroll
            for (int mt = 0; mt < 9; ++mt) {
                int mrow = mt * 16 + lo;
                bf16x8 bb = *(const bf16x8*)(Wt + ((mrow * 128 + ks2 * 64 + hi * 16) ^ ((mrow & 7) << 4)));
                accF[mt] = __builtin_amdgcn_mfma_f32_16x16x32_bf16(a, bb, accF[mt], 0, 0, 0);
            }
        }
    }
    float* pb = pxcs + ((long)s * BATCH + b) * CC * MODES;
    #pragma unroll
    for (int mt = 0; mt < 9; ++mt)
        #pragma unroll
        for (int r = 0; r < 4; ++r)
            pb[(long)(wv * 16 + hi * 4 + r) * MODES + mt * 16 + lo] = accF[mt][r];
}

// ---------- reduce split partials -> xc, xs, x0 (8 lanes per output) ----------
__global__ __launch_bounds__(256) void reduce_kernel(const float* __restrict__ pxcs,
        float* __restrict__ xc, float* __restrict__ xs, float* __restrict__ x0) {
    int gid = blockIdx.x * 256 + threadIdx.x;    // 8 * 36864 = 294912 total
    int idx = gid >> 3, sg = gid & 7;
    float a = 0.f;
    #pragma unroll
    for (int j = 0; j < 16; ++j)
        a += pxcs[(long)(sg * 16 + j) * (BATCH * CC * MODES) + idx];
    a += __shfl_xor(a, 1); a += __shfl_xor(a, 2); a += __shfl_xor(a, 4);
    if (sg == 0) {
        int m = idx % MODES, bc_ = idx / MODES;
        if (m < 64)        xc[bc_ * KK + m] = a;
        else if (m < 128)  xs[bc_ * KK + m - 64] = a;
        else if (m == 128) x0[bc_] = a;
    }
}

// ---------- mix: assemble A=[2fc|-2fs|ww] bf16, f0/wb fp32 ----------
__global__ __launch_bounds__(256) void mix_kernel(const float* __restrict__ xc,
        const float* __restrict__ xs, const float* __restrict__ x0,
        const float* __restrict__ wc, const float* __restrict__ wsp,
        const float* __restrict__ w0, const float* __restrict__ ww,
        const float* __restrict__ wbias, unsigned short* __restrict__ A,
        float* __restrict__ f0a, float* __restrict__ wba, int layer) {
    int o = blockIdx.x, b = blockIdx.y;
    int k = threadIdx.x & 63, ig = threadIdx.x >> 6;
    const float* wcl = wc  + (long)layer * CC * CC * KK;
    const float* wsl = wsp + (long)layer * CC * CC * KK;
    float fc = 0.f, fs = 0.f;
    for (int i = ig * 32; i < ig * 32 + 32; ++i) {
        float xci = xc[(b * CC + i) * KK + k];
        float xsi = xs[(b * CC + i) * KK + k];
        float wcv = wcl[((long)i * CC + o) * KK + k];
        float wsv = wsl[((long)i * CC + o) * KK + k];
        fc += xci * wcv + xsi * wsv;
        fs += xci * wsv - xsi * wcv;
    }
    __shared__ float rc[4][64], rs[4][64];
    rc[ig][k] = fc; rs[ig][k] = fs;
    __syncthreads();
    unsigned short* Ar = A + ((long)b * CC + o) * KTOT;
    if (ig == 0) {
        fc = rc[0][k] + rc[1][k] + rc[2][k] + rc[3][k];
        fs = rs[0][k] + rs[1][k] + rs[2][k] + rs[3][k];
        Ar[k]      = f2bf(2.f * fc);
        Ar[64 + k] = f2bf(-2.f * fs);
    } else if (ig == 1) {
        const float* wwl = ww + ((long)layer * CC + o) * CC;
        Ar[128 + k] = f2bf(wwl[k]);
        Ar[192 + k] = f2bf(wwl[64 + k]);
    } else if (ig == 2) {
        const float* w0l = w0 + (long)layer * CC * CC;
        float p = x0[b * CC + k] * w0l[(long)k * CC + o]
                + x0[b * CC + 64 + k] * w0l[(long)(64 + k) * CC + o];
        #pragma unroll
        for (int off = 32; off > 0; off >>= 1) p += __shfl_down(p, off, 64);
        if (k == 0) { f0a[b * CC + o] = p; wba[b * CC + o] = wbias[layer * CC + o]; }
    }
}

// ---------- fused inverse + next-layer forward partials (T14 prefetch) ----------
// grid (FSPLITS, BATCH), 512 thr = 8 waves; wave tile 16o x 64n; grid-stride over n-chunks.
template <int DO_FWD, int DOGELU>
__global__ __launch_bounds__(512) void fused_inv(const unsigned short* __restrict__ Amat,
        unsigned short* Binv, const unsigned short* __restrict__ wbcs,
        const float* __restrict__ f0a, const float* __restrict__ wba,
        const float* __restrict__ maskp, float* __restrict__ pxcs) {
    int s = blockIdx.x, b = blockIdx.y;
    int t = threadIdx.x, wv = t >> 6, l = t & 63, lo = l & 15, hi = l >> 4;
    __shared__ __align__(16) char lds[51200];
    char* Btile = lds;            // 32 KB staging; overlaid after use by:
    char* Ts    = lds;            //   [64 n][128 o]u16 (16 KB)
    char* Ts2   = lds + 16384;    //   [128 c][64 n]u16 (16 KB)
    char* Wt    = lds + 32768;    // wbcs tile 18432 B
    const unsigned short* Ab = Amat + (long)b * CC * KTOT;
    bf16x8 af[8];
    {
        const unsigned short* arow = Ab + (long)(wv * 16 + lo) * KTOT + hi * 8;
        #pragma unroll
        for (int ks = 0; ks < 8; ++ks) af[ks] = *(const bf16x8*)(arow + ks * 32);
    }
    int o0 = wv * 16 + hi * 4;
    f32x4 f0v = *(const f32x4*)(f0a + b * CC + o0);
    f32x4 wbv = *(const f32x4*)(wba + b * CC + o0);
    int swz = (lo & 7) << 4;
    f32x4 accF[9];
    #pragma unroll
    for (int mt = 0; mt < 9; ++mt) accF[mt] = (f32x4){0.f, 0.f, 0.f, 0.f};
    const char* Wsrc = (const char*)wbcs + (long)b * MODES * NP * 2;
    const char* Bbase = (const char*)Binv + (long)b * NP * 512;

    int off0 = t * 16, off1 = 8192 + t * 16, off2 = 16384 + t * 16;
    uint4 pB0 = {}, pB1 = {}, pB2 = {}, pB3 = {};
    uint4 pW0 = {}, pW1 = {}, pW2 = {};
    {   // prefetch first chunk
        const char* Bsrc = Bbase + (long)s * 64 * 512;
        pB0 = *(const uint4*)(Bsrc + 0 * 8192 + t * 16);
        pB1 = *(const uint4*)(Bsrc + 1 * 8192 + t * 16);
        pB2 = *(const uint4*)(Bsrc + 2 * 8192 + t * 16);
        pB3 = *(const uint4*)(Bsrc + 3 * 8192 + t * 16);
        if (DO_FWD) {
            long n0b = (long)s * 128;
            pW0 = *(const uint4*)(Wsrc + (long)(off0 >> 7) * (NP * 2) + n0b + (off0 & 127));
            pW1 = *(const uint4*)(Wsrc + (long)(off1 >> 7) * (NP * 2) + n0b + (off1 & 127));
            if (t < 128)
                pW2 = *(const uint4*)(Wsrc + (long)(off2 >> 7) * (NP * 2) + n0b + (off2 & 127));
        }
    }

    for (int chunk = s; chunk < NCH; chunk += FSPLITS) {
        int nbase = chunk * 64;
        __syncthreads();   // previous iter's Ts/Ts2/Wt reads complete
        // commit prefetched regs to LDS (swizzled)
        {
            int o = 0 * 8192 + t * 16; *(uint4*)(Btile + (o ^ (((o >> 9) & 7) << 4))) = pB0;
            o = 1 * 8192 + t * 16;     *(uint4*)(Btile + (o ^ (((o >> 9) & 7) << 4))) = pB1;
            o = 2 * 8192 + t * 16;     *(uint4*)(Btile + (o ^ (((o >> 9) & 7) << 4))) = pB2;
            o = 3 * 8192 + t * 16;     *(uint4*)(Btile + (o ^ (((o >> 9) & 7) << 4))) = pB3;
        }
        if (DO_FWD) {
            *(uint4*)(Wt + (off0 ^ (((off0 >> 7) & 7) << 4))) = pW0;
            *(uint4*)(Wt + (off1 ^ (((off1 >> 7) & 7) << 4))) = pW1;
            if (t < 128) *(uint4*)(Wt + (off2 ^ (((off2 >> 7) & 7) << 4))) = pW2;
        }
        // issue next chunk's loads (in flight during MFMA/epilogue)
        int nc = chunk + FSPLITS;
        if (nc < NCH) {
            const char* Bsrc = Bbase + (long)nc * 64 * 512;
            pB0 = *(const uint4*)(Bsrc + 0 * 8192 + t * 16);
            pB1 = *(const uint4*)(Bsrc + 1 * 8192 + t * 16);
            pB2 = *(const uint4*)(Bsrc + 2 * 8192 + t * 16);
            pB3 = *(const uint4*)(Bsrc + 3 * 8192 + t * 16);
            if (DO_FWD) {
                long n0b = (long)nc * 128;
                pW0 = *(const uint4*)(Wsrc + (long)(off0 >> 7) * (NP * 2) + n0b + (off0 & 127));
                pW1 = *(const uint4*)(Wsrc + (long)(off1 >> 7) * (NP * 2) + n0b + (off1 & 127));
                if (t < 128)
                    pW2 = *(const uint4*)(Wsrc + (long)(off2 >> 7) * (NP * 2) + n0b + (off2 & 127));
            }
        }
        __syncthreads();
        f32x4 acc[4];
        #pragma unroll
        for (int fn = 0; fn < 4; ++fn) acc[fn] = (f32x4){0.f, 0.f, 0.f, 0.f};
        #pragma unroll
        for (int ks = 0; ks < 8; ++ks) {
            #pragma unroll
            for (int fn = 0; fn < 4; ++fn) {
                int boff = ((fn * 16 + lo) << 9) + (ks << 6) + (hi << 4);
                bf16x8 bb = *(const bf16x8*)(Btile + (boff ^ swz));
                acc[fn] = __builtin_amdgcn_mfma_f32_16x16x32_bf16(af[ks], bb, acc[fn], 0, 0, 0);
            }
        }
        __syncthreads();   // Btile reads done; overlay with Ts/Ts2
        #pragma unroll
        for (int fn = 0; fn < 4; ++fn) {
            int n = fn * 16 + lo;
            float mv = maskp[(long)b * NP + nbase + n];
            u16x4 pk;
            #pragma unroll
            for (int r = 0; r < 4; ++r) {
                float v = acc[fn][r] + f0v[r] * mv + wbv[r];
                if (DOGELU) v = gelu_exact(v);
                pk[r] = f2bf(v);
                if (DO_FWD)
                    *(unsigned short*)(Ts2 + (((o0 + r) * 128 + n * 2) ^ (((o0 + r) & 7) << 4))) = pk[r];
            }
            *(u16x4*)(Ts + (((n << 8) + (o0 << 1)) ^ ((n & 7) << 4))) = pk;
        }
        __syncthreads();
        char* Bdst = (char*)Binv + ((long)b * NP + nbase) * 512 + 256;
        #pragma unroll
        for (int pass = 0; pass < 2; ++pass) {
            int n = pass * 32 + (t >> 4), seg = t & 15;
            uint4 v = *(const uint4*)(Ts + (((n << 8) + (seg << 4)) ^ ((n & 7) << 4)));
            *(uint4*)(Bdst + (long)n * 512 + seg * 16) = v;
        }
        if (DO_FWD) {
            int ct = wv * 16;
            #pragma unroll
            for (int ks2 = 0; ks2 < 2; ++ks2) {
                int ar = ct + lo;
                bf16x8 a = *(const bf16x8*)(Ts2 + ((ar * 128 + ks2 * 64 + hi * 16) ^ ((ar & 7) << 4)));
                #pragma unroll
                for (int mt = 0; mt < 9; ++mt) {
                    int mrow = mt * 16 + lo;
                    bf16x8 bb = *(const bf16x8*)(Wt + ((mrow * 128 + ks2 * 64 + hi * 16) ^ ((mrow & 7) << 4)));
                    accF[mt] = __builtin_amdgcn_mfma_f32_16x16x32_bf16(a, bb, accF[mt], 0, 0, 0);
                }
            }
        }
    }
    if (DO_FWD) {
        float* pb = pxcs + ((long)s * BATCH + b) * CC * MODES;
        #pragma unroll
        for (int mt = 0; mt < 9; ++mt)
            #pragma unroll
            for (int r = 0; r < 4; ++r)
                pb[(long)(wv * 16 + hi * 4 + r) * MODES + mt * 16 + lo] = accF[mt][r];
    }
}

// ---------- head: out = gelu(hT@fc1 + b1) @ fc2 + b2 ----------
__global__ __launch_bounds__(256) void head_mfma(const unsigned short* __restrict__ Binv,
        const unsigned short* __restrict__ fc1t, const float* __restrict__ b1,
        const float* __restrict__ fc2, const float* __restrict__ b2, float* __restrict__ out) {
    int t = threadIdx.x, wv = t >> 6, l = t & 63, lo = l & 15, hi = l >> 4;
    int b = blockIdx.y;
    int nb = (blockIdx.x * 4 + wv) * 16;
    const unsigned short* Arow = Binv + ((long)b * NP + nb + lo) * KTOT + 128 + hi * 8;
    f32x4 acc[8];
    #pragma unroll
    for (int ft = 0; ft < 8; ++ft) acc[ft] = (f32x4){0.f, 0.f, 0.f, 0.f};
    #pragma unroll
    for (int ks = 0; ks < 4; ++ks) {
        bf16x8 a = *(const bf16x8*)(Arow + ks * 32);
        #pragma unroll
        for (int ft = 0; ft < 8; ++ft) {
            bf16x8 bv = *(const bf16x8*)(fc1t + (ft * 16 + lo) * 128 + ks * 32 + hi * 8);
            acc[ft] = __builtin_amdgcn_mfma_f32_16x16x32_bf16(a, bv, acc[ft], 0, 0, 0);
        }
    }
    float s[4] = {0.f, 0.f, 0.f, 0.f};
    #pragma unroll
    for (int ft = 0; ft < 8; ++ft) {
        int f = ft * 16 + lo;
        float b1f = b1[f], f2f = fc2[f];
        #pragma unroll
        for (int r = 0; r < 4; ++r) s[r] += gelu_exact(acc[ft][r] + b1f) * f2f;
    }
    float b2v = b2[0];
    #pragma unroll
    for (int r = 0; r < 4; ++r) {
        float v = s[r];
        v += __shfl_xor(v, 1); v += __shfl_xor(v, 2);
        v += __shfl_xor(v, 4); v += __shfl_xor(v, 8);
        if (lo == 0) out[(long)b * NN + nb + hi * 4 + r] = v + b2v;
    }
}

extern "C" void kernel_launch(void* const* d_in, const int* in_sizes, int n_in,
                              void* d_out, int out_size, void* d_ws, size_t ws_size,
                              hipStream_t stream) {
    const float* x     = (const float*)d_in[0];
    const float* mask  = (const float*)d_in[1];
    const float* nodes = (const float*)d_in[2];
    const float* wts   = (const float*)d_in[3];
    // d_in[4] directed_edges, d_in[5] edge_gradient_weights: dead (x3 never added)
    const float* modes = (const float*)d_in[6];
    const float* fc0w  = (const float*)d_in[7];
    const float* fc0b  = (const float*)d_in[8];
    const float* spwc  = (const float*)d_in[9];
    const float* spws  = (const float*)d_in[10];
    const float* spw0  = (const float*)d_in[11];
    const float* ww    = (const float*)d_in[12];
    const float* wb    = (const float*)d_in[13];
    // d_in[14] gw_w, d_in[15] gw_b: dead
    const float* fc1w  = (const float*)d_in[16];
    const float* fc1b  = (const float*)d_in[17];
    const float* fc2w  = (const float*)d_in[18];
    const float* fc2b  = (const float*)d_in[19];

    char* p = (char*)d_ws;
    auto alloc = [&](size_t bytes) { char* r = p; p += (bytes + 255) & ~255UL; return r; };
    unsigned short* Binv = (unsigned short*)alloc((size_t)BATCH * NP * KTOT * 2);
    unsigned short* wbcs = (unsigned short*)alloc((size_t)BATCH * MODES * NP * 2);
    unsigned short* Amat = (unsigned short*)alloc((size_t)BATCH * CC * KTOT * 2);
    unsigned short* fc1t = (unsigned short*)alloc((size_t)CC * 128 * 2);
    float* pxcs = (float*)alloc((size_t)FSPLITS * BATCH * CC * MODES * 4);
    float* xcb  = (float*)alloc((size_t)BATCH * CC * KK * 4);
    float* xsb  = (float*)alloc((size_t)BATCH * CC * KK * 4);
    float* x0b  = (float*)alloc((size_t)BATCH * CC * 4);
    float* f0a  = (float*)alloc((size_t)BATCH * CC * 4);
    float* wba  = (float*)alloc((size_t)BATCH * CC * 4);
    float* maskp = (float*)alloc((size_t)BATCH * NP * 4);

    basis_kernel<<<(BATCH * NP) / 256, 256, 0, stream>>>(nodes, mask, wts, modes, wbcs, Binv, maskp);
    fc1t_kernel<<<64, 256, 0, stream>>>(fc1w, fc1t);
    lift_fused<<<dim3(FSPLITS, BATCH), 512, 0, stream>>>(x, fc0w, fc0b, wbcs, Binv, pxcs);

    for (int l = 0; l < NLAYER; ++l) {
        reduce_kernel<<<(8 * BATCH * CC * MODES) / 256, 256, 0, stream>>>(pxcs, xcb, xsb, x0b);
        mix_kernel<<<dim3(CC, BATCH), 256, 0, stream>>>(xcb, xsb, x0b, spwc, spws, spw0,
                                                        ww, wb, Amat, f0a, wba, l);
        if (l < NLAYER - 1)
            fused_inv<1, 1><<<dim3(FSPLITS, BATCH), 512, 0, stream>>>(
                Amat, Binv, wbcs, f0a, wba, maskp, pxcs);
        else
            fused_inv<0, 0><<<dim3(FSPLITS, BATCH), 512, 0, stream>>>(
                Amat, Binv, wbcs, f0a, wba, maskp, pxcs);
    }
    head_mfma<<<dim3(NN / 64, BATCH), 256, 0, stream>>>(Binv, fc1t, fc1b, fc2w, fc2b, (float*)d_out);
}